// Round 5
// baseline (202.247 us; speedup 1.0000x reference)
//
#include <hip/hip_runtime.h>
#include <hip/hip_bf16.h>

// B=2, T=2048, C=1024, H=16, D=64, M = B*T = 4096
#define TT 2048
#define MM 4096

typedef __attribute__((ext_vector_type(8))) short bf16x8;
typedef __attribute__((ext_vector_type(4))) float f32x4;

__device__ inline short f2bf(float f){
  union { float f; unsigned u; } x; x.f = f;
  unsigned r = x.u + 0x7FFFu + ((x.u >> 16) & 1u);
  return (short)(r >> 16);
}
__device__ inline int pk2bf(float a, float b){
  __hip_bfloat162 h2 = __float22bfloat162_rn(make_float2(a, b));
  return *(int*)&h2;
}

// async global->LDS, 16B per lane; LDS dest must be wave-uniform base + lane*16
__device__ inline void async16(const void* g, void* l){
  __builtin_amdgcn_global_load_lds((const __attribute__((address_space(1))) void*)g,
                                   (__attribute__((address_space(3))) void*)l, 16, 0, 0);
}

// ---------------- fused fp32 -> bf16 convert (x + 4 weights, one launch) ----------------
__global__ void cvt_all(const float* __restrict__ x,
                        const float* __restrict__ Wq, const float* __restrict__ Wk,
                        const float* __restrict__ Wv, const float* __restrict__ Wp,
                        short* __restrict__ xb, short* __restrict__ Wqb, short* __restrict__ Wkb,
                        short* __restrict__ Wvb, short* __restrict__ Wpb){
  int b = blockIdx.x;
  const float* in; short* out; int base;
  if (b < 4096)      { in = x;  out = xb;  base = b; }
  else if (b < 5120) { in = Wq; out = Wqb; base = b - 4096; }
  else if (b < 6144) { in = Wk; out = Wkb; base = b - 5120; }
  else if (b < 7168) { in = Wv; out = Wvb; base = b - 6144; }
  else               { in = Wp; out = Wpb; base = b - 7168; }
  int i = base * 256 + threadIdx.x;
  float4 v = ((const float4*)in)[i];
  short4 o;
  o.x = f2bf(v.x); o.y = f2bf(v.y); o.z = f2bf(v.z); o.w = f2bf(v.w);
  ((short4*)out)[i] = o;
}

// ---------------- GEMM core: 128x128 tile, dbuf single-barrier pipeline (attn-style) ----------------
// Round-4 theory: the old two-barrier-per-kt structure exposed full load latency at each barrier's
// implicit vmcnt(0) drain (measured ~6000 cyc/kt vs ~2300 cyc LDS wall). Now: stage tile kt+1 right
// AFTER the single barrier, compute tile kt meanwhile; the next barrier's drain hits loads issued a
// full compute-phase ago. LDS doubles to 64KB/block -> 2 blocks/CU.
__device__ inline void stage_qkv(const short* Ap0, const short* Ap1,
                                 const short* Bp0, const short* Bp1,
                                 int kk, short* As, short* Bs, int tid){
#pragma unroll
  for (int pn = 0; pn < 2; ++pn){
    async16(Ap0 + kk + pn*32, As + pn*4096 + (size_t)tid * 8);
    async16(Ap1 + kk + pn*32, As + pn*4096 + (size_t)(tid + 256) * 8);
    async16(Bp0 + kk + pn*32, Bs + pn*4096 + (size_t)tid * 8);
    async16(Bp1 + kk + pn*32, Bs + pn*4096 + (size_t)(tid + 256) * 8);
  }
}

__device__ inline void gemm_core(const short* __restrict__ A, const short* __restrict__ Wm,
                                 short* As, short* Bs, int m0, int n0,
                                 int tid, int wm, int wn, int quad, int lr,
                                 f32x4 acc[4][4])
{
  const int prow = tid >> 2, pcol = (tid & 3) << 3;
  const short* Ap0 = A  + (size_t)(m0 + prow) * 1024 + pcol;
  const short* Ap1 = Ap0 + 64 * 1024;
  const short* Bp0 = Wm + (size_t)(n0 + prow) * 1024 + pcol;
  const short* Bp1 = Bp0 + 64 * 1024;

  stage_qkv(Ap0, Ap1, Bp0, Bp1, 0, As, Bs, tid);      // prologue: tile 0 -> buf 0
  int cur = 0;
  for (int kt = 0; kt < 16; ++kt){
    __syncthreads();                                   // buf[cur] ready; prior reads of buf[cur^1] done
    if (kt + 1 < 16)
      stage_qkv(Ap0, Ap1, Bp0, Bp1, (kt+1)*64, As + (cur^1)*8192, Bs + (cur^1)*8192, tid);
#pragma unroll
    for (int ks = 0; ks < 2; ++ks){
      bf16x8 aF[4], bF[4];
#pragma unroll
      for (int mt = 0; mt < 4; ++mt) aF[mt] = *(const bf16x8*)(As + cur*8192 + ks*4096 + (wm*64 + mt*16 + lr)*32 + quad*8);
#pragma unroll
      for (int nt = 0; nt < 4; ++nt) bF[nt] = *(const bf16x8*)(Bs + cur*8192 + ks*4096 + (wn*64 + nt*16 + lr)*32 + quad*8);
#pragma unroll
      for (int mt = 0; mt < 4; ++mt)
#pragma unroll
        for (int nt = 0; nt < 4; ++nt)
          acc[mt][nt] = __builtin_amdgcn_mfma_f32_16x16x32_bf16(aF[mt], bF[nt], acc[mt][nt], 0, 0, 0);
    }
    cur ^= 1;
  }
}

// ---------------- QKV projection: Q,K as [B,H,T,D] (Q pre-scaled), V as [B,H,D,T] ----------------
__launch_bounds__(256, 2)
__global__ void gemm_qkv(const short* __restrict__ A,
                         const short* __restrict__ W0, const short* __restrict__ W1, const short* __restrict__ W2,
                         const float* __restrict__ b0, const float* __restrict__ b1, const float* __restrict__ b2,
                         short* __restrict__ Qo, short* __restrict__ Ko, short* __restrict__ Vt)
{
  __shared__ __align__(16) short As[2*8192];   // [buf][2 panels][128x32]
  __shared__ __align__(16) short Bs[2*8192];
  short* smem = As;                            // epilogue scratch reuse (needs <= 9216 shorts)
  const int z = blockIdx.z;
  const short* Wm   = (z == 0) ? W0 : ((z == 1) ? W1 : W2);
  const float* bias = (z == 0) ? b0 : ((z == 1) ? b1 : b2);
  const int tid = threadIdx.x;
  const int lane = tid & 63, wave = tid >> 6;
  const int wm = wave >> 1, wn = wave & 1;
  const int quad = lane >> 4, lr = lane & 15;
  const int m0 = blockIdx.y * 128, n0 = blockIdx.x * 128;

  f32x4 acc[4][4];
#pragma unroll
  for (int i = 0; i < 4; ++i)
#pragma unroll
    for (int j = 0; j < 4; ++j)
#pragma unroll
      for (int r = 0; r < 4; ++r) acc[i][j][r] = 0.f;

  gemm_core(A, Wm, As, Bs, m0, n0, tid, wm, wn, quad, lr, acc);

  const float qscale = 0.125f * 1.4426950408889634f;  // scale/sqrt(D) * log2(e) folded into Q
  const int bB = m0 >> 11, t0 = m0 & 2047;

  if (z == 2){
    // V: transpose in LDS -> coalesced [B,H,D,T] stores
#pragma unroll
    for (int nh = 0; nh < 2; ++nh){
      __syncthreads();
      if (wn == nh){
#pragma unroll
        for (int nt = 0; nt < 4; ++nt){
          int n = n0 + wn*64 + nt*16 + lr;
          float bv = bias[n];
          int n_l = nt*16 + lr;
#pragma unroll
          for (int mt = 0; mt < 4; ++mt)
#pragma unroll
            for (int r = 0; r < 4; ++r){
              int m_l = wm*64 + mt*16 + quad*4 + r;
              smem[n_l*136 + m_l] = f2bf(acc[mt][nt][r] + bv);
            }
        }
      }
      __syncthreads();
#pragma unroll
      for (int i = 0; i < 4; ++i){
        int c = tid + i*256;
        int rowN = c >> 4, ch = c & 15;
        int4 v = *(const int4*)(smem + rowN*136 + ch*8);
        int n = n0 + nh*64 + rowN;
        int hH = n >> 6, d = n & 63;
        *(int4*)(Vt + ((size_t)((bB<<4) + hH)*64 + d)*2048 + t0 + ch*8) = v;
      }
    }
    return;
  }

  // Q/K: stage [m][n] tile half-by-half in LDS (stride 72), then coalesced int4 row stores
  short* dst = (z == 0) ? Qo : Ko;
#pragma unroll
  for (int nh = 0; nh < 2; ++nh){
    __syncthreads();
    if (wn == nh){
#pragma unroll
      for (int nt = 0; nt < 4; ++nt){
        int n_l = nt*16 + lr;
        float bv = bias[n0 + nh*64 + n_l];
#pragma unroll
        for (int mt = 0; mt < 4; ++mt){
#pragma unroll
          for (int r = 0; r < 4; ++r){
            int m_l = wm*64 + mt*16 + quad*4 + r;
            float v = acc[mt][nt][r] + bv;
            if (z == 0) v *= qscale;
            smem[m_l*72 + n_l] = f2bf(v);
          }
        }
      }
    }
    __syncthreads();
    const int hH = (n0 + nh*64) >> 6;
    short* dhead = dst + (size_t)((bB<<4) + hH) * 2048 * 64;
#pragma unroll
    for (int i = 0; i < 4; ++i){
      int c = tid + i*256;
      int rowm = c >> 3, ch = (c & 7) << 3;
      int4 v = *(const int4*)(smem + rowm*72 + ch);
      *(int4*)(dhead + (size_t)(t0 + rowm)*64 + ch) = v;
    }
  }
}

// ---------------- output projection: 128x64 tiles, dbuf single-barrier pipeline ----------------
__launch_bounds__(256, 2)
__global__ void gemm_proj(const short* __restrict__ A, const short* __restrict__ Wm,
                          const float* __restrict__ bias, float* __restrict__ out)
{
  __shared__ __align__(16) short As[2*8192];   // [buf][2 panels][128x32]
  __shared__ __align__(16) short Bs[2*4096];   // [buf][2 panels][64x32]
  const int tid = threadIdx.x;
  const int lane = tid & 63, wave = tid >> 6;
  const int quad = lane >> 4, lr = lane & 15;
  const int m0 = blockIdx.y * 128, n0 = blockIdx.x * 64;

  const int prow = tid >> 2, pcol = (tid & 3) << 3;
  const short* Ap0 = A  + (size_t)(m0 + prow) * 1024 + pcol;
  const short* Ap1 = Ap0 + 64 * 1024;
  const short* Bp0 = Wm + (size_t)(n0 + prow) * 1024 + pcol;

  f32x4 acc[2][4];
#pragma unroll
  for (int i = 0; i < 2; ++i)
#pragma unroll
    for (int j = 0; j < 4; ++j)
#pragma unroll
      for (int r = 0; r < 4; ++r) acc[i][j][r] = 0.f;

  // prologue: tile 0 -> buf 0
#pragma unroll
  for (int pn = 0; pn < 2; ++pn){
    async16(Ap0 + pn*32, As + pn*4096 + (size_t)tid * 8);
    async16(Ap1 + pn*32, As + pn*4096 + (size_t)(tid + 256) * 8);
    async16(Bp0 + pn*32, Bs + pn*2048 + (size_t)tid * 8);
  }
  int cur = 0;
  for (int kt = 0; kt < 16; ++kt){
    __syncthreads();                    // buf[cur] ready; prior reads of buf[cur^1] done
    if (kt + 1 < 16){
      const int kk = (kt + 1) * 64;
      short* Ad = As + (cur^1)*8192;
      short* Bd = Bs + (cur^1)*4096;
#pragma unroll
      for (int pn = 0; pn < 2; ++pn){
        async16(Ap0 + kk + pn*32, Ad + pn*4096 + (size_t)tid * 8);
        async16(Ap1 + kk + pn*32, Ad + pn*4096 + (size_t)(tid + 256) * 8);
        async16(Bp0 + kk + pn*32, Bd + pn*2048 + (size_t)tid * 8);
      }
    }
#pragma unroll
    for (int ks = 0; ks < 2; ++ks){
      bf16x8 aF[2], bF[4];
#pragma unroll
      for (int mt = 0; mt < 2; ++mt) aF[mt] = *(const bf16x8*)(As + cur*8192 + ks*4096 + (wave*32 + mt*16 + lr)*32 + quad*8);
#pragma unroll
      for (int nt = 0; nt < 4; ++nt) bF[nt] = *(const bf16x8*)(Bs + cur*4096 + ks*2048 + (nt*16 + lr)*32 + quad*8);
#pragma unroll
      for (int mt = 0; mt < 2; ++mt)
#pragma unroll
        for (int nt = 0; nt < 4; ++nt)
          acc[mt][nt] = __builtin_amdgcn_mfma_f32_16x16x32_bf16(aF[mt], bF[nt], acc[mt][nt], 0, 0, 0);
    }
    cur ^= 1;
  }

#pragma unroll
  for (int nt = 0; nt < 4; ++nt){
    int n = n0 + nt*16 + lr;
    float bv = bias[n];
#pragma unroll
    for (int mt = 0; mt < 2; ++mt){
      int mBase = m0 + wave*32 + mt*16 + quad*4;
#pragma unroll
      for (int r = 0; r < 4; ++r){
        int m = mBase + r;
        out[(size_t)m * 1024 + n] = acc[mt][nt][r] + bv;
      }
    }
  }
}

// ---------------- flash attention (causal): 128-row bands, 32 q/wave, 3 blocks/CU ----------------
// Q (pre-scaled by log2e/8), K: [B*H, T, 64] bf16 ; Vt: [B*H, 64, T] bf16 ; AO: [B*T, 1024] bf16
// Verified R4 schedule: 3 co-resident tasks per CU run in PARALLEL; per-CU sum = 34 steps with
// mixed lengths. Bands qb>=8 KV-split into exact-additive halves; combine normalizes t>=1024.
// slice_tbl entry: (qb<<11) | (kv_start<<6) | kv_len ; row a = CU slice, col j = dispatch wave.
__device__ __constant__ int slice_tbl[24] = {
  14352, 30736,     2,   // a=0: U7(16),  Ha15(16), U0(2)
  31760, 26638,  2052,   // a=1: Hb15(16), Ha13(14), U1(4)
  12302, 27534,  4102,   // a=2: U6(14),  Hb13(14), U2(6)
  28687, 20491,  6152,   // a=3: Ha14(15), Ha10(11), U3(8)
  29647, 19082, 16393,   // a=4: Hb14(15), Hb9(10),  Ha8(9)
  24589, 10252, 16969,   // a=5: Ha12(13), U5(12),  Hb8(9)
  25421, 21195,  8202,   // a=6: Hb12(13), Hb10(11), U4(10)
  22540, 23308, 18442    // a=7: Ha11(12), Hb11(12), Ha9(10)
};

__launch_bounds__(256, 3)
__global__ void attn_kernel(const short* __restrict__ Q, const short* __restrict__ K,
                            const short* __restrict__ Vt, short* __restrict__ AO,
                            float* __restrict__ Opart, float* __restrict__ Lpart)
{
  __shared__ __align__(16) short Ks[2][4096];   // [buf][64 rows x 64 shorts], swizzled
  __shared__ __align__(16) short Vs[2][4096];
  __shared__ __align__(16) short Ps[8192];      // per-wave 2x(16x64) P^T/O^T scratch, swizzled
  const int tid = threadIdx.x, lane = tid & 63, wave = tid >> 6;
  const int quad = lane >> 4, lr = lane & 15;
  const int bid = blockIdx.x;
  const int a = (bid >> 5) & 7;                // CU slice
  const int hb = bid & 31;
  const int j = bid >> 8;                      // dispatch wave 0..2 (j*256 apart -> same CU)
  const int e = slice_tbl[a*3 + j];
  const int qb = e >> 11, kv_s = (e >> 6) & 31, kvn = e & 63;
  const bool split = (kvn != 2*qb + 2);
  const int half = (kv_s != 0) ? 1 : 0;
  const int bidx = hb >> 4, h = hb & 15;
  const int wq0 = qb * 128 + wave * 32;        // this wave's 32 q-rows (two 16-row groups)
  const short* Qh = Q  + (size_t)hb * TT * 64;
  const short* Kh = K  + (size_t)hb * TT * 64;
  const short* Vh = Vt + (size_t)hb * 64 * TT;
  short* Pw = Ps + wave * 2048;                // two 1024-short regions (one per q-group)

  // staging: chunk c = tid covers (row = c>>3, swizzled col-chunk); c+256 = row+32, same swizzle
  const int srow = tid >> 3;
  const int ssw  = (tid & 7) ^ (srow & 7);
  const short* Kp0 = Kh + (size_t)srow * 64 + ssw * 8;
  const short* Vp0 = Vh + (size_t)srow * TT + ssw * 8;

  // loop-invariant Q fragments (B-operand: n = lr = q), one pair per q-group
  bf16x8 qf[2][2];
#pragma unroll
  for (int g = 0; g < 2; ++g)
#pragma unroll
    for (int ks = 0; ks < 2; ++ks)
      qf[g][ks] = *(const bf16x8*)(Qh + (size_t)(wq0 + g*16 + lr) * 64 + ks*32 + quad*8);

  // swizzled frag-read chunk offsets (loop-invariant): chunk ks*4+quad, row-phase lr&7
  const int lsw0 = (((0*4 + quad) ^ (lr & 7)) << 3);
  const int lsw1 = (((1*4 + quad) ^ (lr & 7)) << 3);
  const int qh2 = quad >> 1, qlo = (quad & 1) << 2;

  f32x4 acc_o[2][4], l_acc[2];
#pragma unroll
  for (int g = 0; g < 2; ++g){
#pragma unroll
    for (int r = 0; r < 4; ++r) l_acc[g][r] = 0.f;
#pragma unroll
    for (int dt = 0; dt < 4; ++dt)
#pragma unroll
      for (int r = 0; r < 4; ++r) acc_o[g][dt][r] = 0.f;
  }

  const short one_bf = (short)0x3F80;
  const bf16x8 onesf = { one_bf, one_bf, one_bf, one_bf, one_bf, one_bf, one_bf, one_bf };

  const int kv_e = kv_s + kvn;
  const int qtw = wq0 >> 6;                    // wave's diagonal KV-tile (both q-groups share it)
  // prologue: stage tile kv_s into buffer 0 (async)
  {
    const short* kp = Kp0 + (size_t)kv_s * 4096;
    const short* vp = Vp0 + kv_s * 64;
    async16(kp,          &Ks[0][(size_t)tid * 8]);
    async16(kp + 32*64,  &Ks[0][(size_t)(tid + 256) * 8]);
    async16(vp,          &Vs[0][(size_t)tid * 8]);
    async16(vp + 32*TT,  &Vs[0][(size_t)(tid + 256) * 8]);
  }

  // strength-reduced next-tile staging pointers
  const short* kp_n = Kp0 + (size_t)(kv_s + 1) * 4096;
  const short* vp_n = Vp0 + (kv_s + 1) * 64;

  int cur = 0;
  for (int kv = kv_s; kv < kv_e; ++kv){
    const int kv0 = kv * 64;
    __syncthreads();                     // drains vmcnt: buf[cur] ready; prior reads of buf[cur^1] done
    if (kv + 1 < kv_e){                  // async stage tile kv+1 into the other buffer
      const int nb = cur ^ 1;
      async16(kp_n,          &Ks[nb][(size_t)tid * 8]);
      async16(kp_n + 32*64,  &Ks[nb][(size_t)(tid + 256) * 8]);
      async16(vp_n,          &Vs[nb][(size_t)tid * 8]);
      async16(vp_n + 32*TT,  &Vs[nb][(size_t)(tid + 256) * 8]);
      kp_n += 4096; vp_n += 64;
    }
    if (kv0 <= wq0 + 31){
      // S^T = K Q^T for both q-groups; each kf fragment read once, used twice
      f32x4 s4[2][4];
#pragma unroll
      for (int g = 0; g < 2; ++g)
#pragma unroll
        for (int nt = 0; nt < 4; ++nt)
#pragma unroll
          for (int r = 0; r < 4; ++r) s4[g][nt][r] = 0.f;
#pragma unroll
      for (int nt = 0; nt < 4; ++nt){
        bf16x8 kf0 = *(const bf16x8*)(&Ks[cur][(nt*16 + lr)*64 + lsw0]);
        bf16x8 kf1 = *(const bf16x8*)(&Ks[cur][(nt*16 + lr)*64 + lsw1]);
#pragma unroll
        for (int g = 0; g < 2; ++g){
          s4[g][nt] = __builtin_amdgcn_mfma_f32_16x16x32_bf16(kf0, qf[g][0], s4[g][nt], 0, 0, 0);
          s4[g][nt] = __builtin_amdgcn_mfma_f32_16x16x32_bf16(kf1, qf[g][1], s4[g][nt], 0, 0, 0);
        }
      }

      // P^T = exp2(S^T); diagonal-tile masking hoisted into a wave-uniform branch
      if (kv == qtw){
#pragma unroll
        for (int g = 0; g < 2; ++g){
          const int qglob = wq0 + g*16 + lr;
          short* Pg = Pw + g*1024;
#pragma unroll
          for (int nt = 0; nt < 4; ++nt){
            const int keyb = kv0 + nt*16 + quad*4;
            float pv[4];
#pragma unroll
            for (int r = 0; r < 4; ++r){
              float v = exp2f(s4[g][nt][r]);
              if (keyb + r > qglob) v = 0.f;
              pv[r] = v;
            }
            int2 w;
            w.x = pk2bf(pv[0], pv[1]);
            w.y = pk2bf(pv[2], pv[3]);
            const int gg = nt*2 + qh2;
            *(int2*)(Pg + lr*64 + ((gg ^ (lr & 7)) << 3) + qlo) = w;
          }
        }
      } else {
#pragma unroll
        for (int g = 0; g < 2; ++g){
          short* Pg = Pw + g*1024;
#pragma unroll
          for (int nt = 0; nt < 4; ++nt){
            int2 w;
            w.x = pk2bf(exp2f(s4[g][nt][0]), exp2f(s4[g][nt][1]));
            w.y = pk2bf(exp2f(s4[g][nt][2]), exp2f(s4[g][nt][3]));
            const int gg = nt*2 + qh2;
            *(int2*)(Pg + lr*64 + ((gg ^ (lr & 7)) << 3) + qlo) = w;
          }
        }
      }
      // wave-private Pw: lgkmcnt ordering only, no barrier

      // l += 1^T P^T ; O^T += V^T P^T ; each vf fragment read once, used twice
#pragma unroll
      for (int ks = 0; ks < 2; ++ks){
        const int lsw = ks ? lsw1 : lsw0;
        bf16x8 ptf0 = *(const bf16x8*)(Pw + lr*64 + lsw);
        bf16x8 ptf1 = *(const bf16x8*)(Pw + 1024 + lr*64 + lsw);
        l_acc[0] = __builtin_amdgcn_mfma_f32_16x16x32_bf16(onesf, ptf0, l_acc[0], 0, 0, 0);
        l_acc[1] = __builtin_amdgcn_mfma_f32_16x16x32_bf16(onesf, ptf1, l_acc[1], 0, 0, 0);
#pragma unroll
        for (int dt = 0; dt < 4; ++dt){
          bf16x8 vf = *(const bf16x8*)(&Vs[cur][(dt*16 + lr)*64 + lsw]);
          acc_o[0][dt] = __builtin_amdgcn_mfma_f32_16x16x32_bf16(vf, ptf0, acc_o[0][dt], 0, 0, 0);
          acc_o[1][dt] = __builtin_amdgcn_mfma_f32_16x16x32_bf16(vf, ptf1, acc_o[1][dt], 0, 0, 0);
        }
      }
    }
    cur ^= 1;
  }

  if (split){
    // partial epilogue: raw fp32 O + l to workspace; exact additive combine later (no max-rescale)
    const int p = (((hb << 3) | (qb - 8)) << 1) + half;
    float* Op = Opart + (size_t)p * 8192;     // [128 q][64 d] f32
#pragma unroll
    for (int g = 0; g < 2; ++g){
      const int q_l = wave*32 + g*16 + lr;
#pragma unroll
      for (int dt = 0; dt < 4; ++dt)
        *(f32x4*)(Op + q_l*64 + dt*16 + quad*4) = acc_o[g][dt];
      if (lane < 16) Lpart[p*128 + wave*32 + g*16 + lane] = l_acc[g][0];
    }
    return;
  }

  // epilogue (unsplit): O = O^T / l per q-group; transpose via swizzled wave-private LDS -> int4 stores
#pragma unroll
  for (int g = 0; g < 2; ++g){
    short* Pg = Pw + g*1024;
    const float inv = __builtin_amdgcn_rcpf(l_acc[g][0]);   // all regs equal l[q=lr]
#pragma unroll
    for (int dt = 0; dt < 4; ++dt){
      int2 w;
      w.x = pk2bf(acc_o[g][dt][0] * inv, acc_o[g][dt][1] * inv);
      w.y = pk2bf(acc_o[g][dt][2] * inv, acc_o[g][dt][3] * inv);
      const int gg = dt*2 + qh2;
      *(int2*)(Pg + lr*64 + ((gg ^ (lr & 7)) << 3) + qlo) = w;
    }
    // wave-private: compiler inserts lgkmcnt wait before the reads below
#pragma unroll
    for (int i = 0; i < 2; ++i){
      int c = lane + i*64;               // 128 chunks: 16 q-rows x 8 chunks of 8 shorts
      int row = c >> 3, ch = c & 7;
      int4 v = *(const int4*)(Pg + row*64 + ((ch ^ (row & 7)) << 3));
      *(int4*)(AO + (size_t)(bidx*2048 + wq0 + g*16 + row)*1024 + h*64 + ch*8) = v;
    }
  }
}

// ---------------- combine: O = (O0+O1)/(l0+l1) for split bands (t >= 1024 per batch) ----------------
__global__ void attn_combine(const float* __restrict__ Opart, const float* __restrict__ Lpart,
                             short* __restrict__ AO)
{
  const int gid = blockIdx.x * 256 + threadIdx.x;  // 524288 = 32768 rows x 16 d-quads
  const int row = gid >> 4, dq = (gid & 15) << 2;
  const int hb = row >> 10, band = (row >> 7) & 7, r = row & 127;
  const int p = ((hb << 3) | band) << 1;
  const f32x4 a = *(const f32x4*)(Opart + (size_t)p*8192 + r*64 + dq);
  const f32x4 b = *(const f32x4*)(Opart + (size_t)(p+1)*8192 + r*64 + dq);
  const float l = Lpart[p*128 + r] + Lpart[(p+1)*128 + r];
  const float inv = __builtin_amdgcn_rcpf(l);
  int2 w;
  w.x = pk2bf((a[0]+b[0])*inv, (a[1]+b[1])*inv);
  w.y = pk2bf((a[2]+b[2])*inv, (a[3]+b[3])*inv);
  const int t = (8 + band)*128 + r;
  const int bidx = hb >> 4, h = hb & 15;
  *(int2*)(AO + (size_t)(bidx*2048 + t)*1024 + h*64 + dq) = w;
}

extern "C" void kernel_launch(void* const* d_in, const int* in_sizes, int n_in,
                              void* d_out, int out_size, void* d_ws, size_t ws_size,
                              hipStream_t stream)
{
  const float* x  = (const float*)d_in[0];
  const float* Wq = (const float*)d_in[1];
  const float* bq = (const float*)d_in[2];
  const float* Wk = (const float*)d_in[3];
  const float* bk = (const float*)d_in[4];
  const float* Wv = (const float*)d_in[5];
  const float* bv = (const float*)d_in[6];
  const float* Wp = (const float*)d_in[7];
  const float* bp = (const float*)d_in[8];
  float* out = (float*)d_out;

  char* ws = (char*)d_ws;
  const size_t MB = 1024ull * 1024ull;
  short* Qb  = (short*)(ws + 0);        // [B,H,T,D] bf16 (pre-scaled by log2e/8)
  short* Kb  = (short*)(ws + 8*MB);     // [B,H,T,D] bf16
  short* Vtb = (short*)(ws + 16*MB);    // [B,H,D,T] bf16
  short* AOb = (short*)(ws + 24*MB);    // [B*T, C] bf16 — aliases xb (qkv reads finish first)
  short* xb  = (short*)(ws + 24*MB);    // [M, C] bf16
  short* Wqb = (short*)(ws + 32*MB);
  short* Wkb = (short*)(ws + 34*MB);
  short* Wvb = (short*)(ws + 36*MB);
  short* Wpb = (short*)(ws + 38*MB);
  float* Opart = (float*)(ws + 40*MB);  // 512 x 128x64 f32 partial O (16 MB)
  float* Lpart = (float*)(ws + 56*MB);  // 512 x 128 f32 partial l (256 KB)

  cvt_all<<<8192, 256, 0, stream>>>(x, Wq, Wk, Wv, Wp, xb, Wqb, Wkb, Wvb, Wpb);
  gemm_qkv<<<dim3(8, 32, 3), 256, 0, stream>>>(xb, Wqb, Wkb, Wvb, bq, bk, bv, Qb, Kb, Vtb);
  attn_kernel<<<768, 256, 0, stream>>>(Qb, Kb, Vtb, AOb, Opart, Lpart);
  attn_combine<<<2048, 256, 0, stream>>>(Opart, Lpart, AOb);
  gemm_proj<<<dim3(16, 32), 256, 0, stream>>>(AOb, Wpb, bp, out);
}

// Round 6
// 188.577 us; speedup vs baseline: 1.0725x; 1.0725x over previous
//
#include <hip/hip_runtime.h>
#include <hip/hip_bf16.h>

// B=2, T=2048, C=1024, H=16, D=64, M = B*T = 4096
#define TT 2048
#define MM 4096

typedef __attribute__((ext_vector_type(8))) short bf16x8;
typedef __attribute__((ext_vector_type(4))) float f32x4;

__device__ inline short f2bf(float f){
  union { float f; unsigned u; } x; x.f = f;
  unsigned r = x.u + 0x7FFFu + ((x.u >> 16) & 1u);
  return (short)(r >> 16);
}
__device__ inline int pk2bf(float a, float b){
  __hip_bfloat162 h2 = __float22bfloat162_rn(make_float2(a, b));
  return *(int*)&h2;
}

// async global->LDS, 16B per lane; LDS dest must be wave-uniform base + lane*16
__device__ inline void async16(const void* g, void* l){
  __builtin_amdgcn_global_load_lds((const __attribute__((address_space(1))) void*)g,
                                   (__attribute__((address_space(3))) void*)l, 16, 0, 0);
}

// ---------------- fused fp32 -> bf16 convert (x + 4 weights, one launch) ----------------
__global__ void cvt_all(const float* __restrict__ x,
                        const float* __restrict__ Wq, const float* __restrict__ Wk,
                        const float* __restrict__ Wv, const float* __restrict__ Wp,
                        short* __restrict__ xb, short* __restrict__ Wqb, short* __restrict__ Wkb,
                        short* __restrict__ Wvb, short* __restrict__ Wpb){
  int b = blockIdx.x;
  const float* in; short* out; int base;
  if (b < 4096)      { in = x;  out = xb;  base = b; }
  else if (b < 5120) { in = Wq; out = Wqb; base = b - 4096; }
  else if (b < 6144) { in = Wk; out = Wkb; base = b - 5120; }
  else if (b < 7168) { in = Wv; out = Wvb; base = b - 6144; }
  else               { in = Wp; out = Wpb; base = b - 7168; }
  int i = base * 256 + threadIdx.x;
  float4 v = ((const float4*)in)[i];
  short4 o;
  o.x = f2bf(v.x); o.y = f2bf(v.y); o.z = f2bf(v.z); o.w = f2bf(v.w);
  ((short4*)out)[i] = o;
}

// ---------------- GEMM core: 128x128 tile, BK=64 as two BK=32 panels, two-barrier (proven) ----------------
// R5 post-mortem: single-barrier dbuf (64KB LDS, 2 blocks/CU) LOST to this structure (32KB,
// 3 blocks/CU): cross-block TLP covers the barrier drain better than intra-block pipelining.
// k0/nkt parametrize a K-range so gemm_proj can K-split while reusing the identical core.
__device__ inline void gemm_core(const short* __restrict__ A, const short* __restrict__ Wm,
                                 short* As, short* Bs, int m0, int n0, int k0, int nkt,
                                 int tid, int wm, int wn, int quad, int lr,
                                 f32x4 acc[4][4])
{
  const int prow = tid >> 2, pcol = (tid & 3) << 3;
  const short* Ap0 = A  + (size_t)(m0 + prow) * 1024 + k0 + pcol;
  const short* Ap1 = Ap0 + 64 * 1024;
  const short* Bp0 = Wm + (size_t)(n0 + prow) * 1024 + k0 + pcol;
  const short* Bp1 = Bp0 + 64 * 1024;
  for (int kt = 0; kt < nkt; ++kt){
    const int kk = kt * 64;
#pragma unroll
    for (int pn = 0; pn < 2; ++pn){
      async16(Ap0 + kk + pn*32, As + pn*4096 + (size_t)tid * 8);
      async16(Ap1 + kk + pn*32, As + pn*4096 + (size_t)(tid + 256) * 8);
      async16(Bp0 + kk + pn*32, Bs + pn*4096 + (size_t)tid * 8);
      async16(Bp1 + kk + pn*32, Bs + pn*4096 + (size_t)(tid + 256) * 8);
    }
    __syncthreads();
#pragma unroll
    for (int ks = 0; ks < 2; ++ks){
      bf16x8 aF[4], bF[4];
#pragma unroll
      for (int mt = 0; mt < 4; ++mt) aF[mt] = *(const bf16x8*)(As + ks*4096 + (wm*64 + mt*16 + lr)*32 + quad*8);
#pragma unroll
      for (int nt = 0; nt < 4; ++nt) bF[nt] = *(const bf16x8*)(Bs + ks*4096 + (wn*64 + nt*16 + lr)*32 + quad*8);
#pragma unroll
      for (int mt = 0; mt < 4; ++mt)
#pragma unroll
        for (int nt = 0; nt < 4; ++nt)
          acc[mt][nt] = __builtin_amdgcn_mfma_f32_16x16x32_bf16(aF[mt], bF[nt], acc[mt][nt], 0, 0, 0);
    }
    __syncthreads();
  }
}

// ---------------- QKV projection: Q,K as [B,H,T,D] (Q pre-scaled), V as [B,H,D,T] ----------------
__launch_bounds__(256, 3)
__global__ void gemm_qkv(const short* __restrict__ A,
                         const short* __restrict__ W0, const short* __restrict__ W1, const short* __restrict__ W2,
                         const float* __restrict__ b0, const float* __restrict__ b1, const float* __restrict__ b2,
                         short* __restrict__ Qo, short* __restrict__ Ko, short* __restrict__ Vt)
{
  __shared__ __align__(16) short smem[16384];
  short* As = smem;
  short* Bs = smem + 8192;
  const int z = blockIdx.z;
  const short* Wm   = (z == 0) ? W0 : ((z == 1) ? W1 : W2);
  const float* bias = (z == 0) ? b0 : ((z == 1) ? b1 : b2);
  const int tid = threadIdx.x;
  const int lane = tid & 63, wave = tid >> 6;
  const int wm = wave >> 1, wn = wave & 1;
  const int quad = lane >> 4, lr = lane & 15;
  const int m0 = blockIdx.y * 128, n0 = blockIdx.x * 128;

  f32x4 acc[4][4];
#pragma unroll
  for (int i = 0; i < 4; ++i)
#pragma unroll
    for (int j = 0; j < 4; ++j)
#pragma unroll
      for (int r = 0; r < 4; ++r) acc[i][j][r] = 0.f;

  gemm_core(A, Wm, As, Bs, m0, n0, 0, 16, tid, wm, wn, quad, lr, acc);

  const float qscale = 0.125f * 1.4426950408889634f;  // scale/sqrt(D) * log2(e) folded into Q
  const int bB = m0 >> 11, t0 = m0 & 2047;

  if (z == 2){
    // V: transpose in LDS -> coalesced [B,H,D,T] stores
#pragma unroll
    for (int nh = 0; nh < 2; ++nh){
      __syncthreads();
      if (wn == nh){
#pragma unroll
        for (int nt = 0; nt < 4; ++nt){
          int n = n0 + wn*64 + nt*16 + lr;
          float bv = bias[n];
          int n_l = nt*16 + lr;
#pragma unroll
          for (int mt = 0; mt < 4; ++mt)
#pragma unroll
            for (int r = 0; r < 4; ++r){
              int m_l = wm*64 + mt*16 + quad*4 + r;
              smem[n_l*136 + m_l] = f2bf(acc[mt][nt][r] + bv);
            }
        }
      }
      __syncthreads();
#pragma unroll
      for (int i = 0; i < 4; ++i){
        int c = tid + i*256;
        int rowN = c >> 4, ch = c & 15;
        int4 v = *(const int4*)(smem + rowN*136 + ch*8);
        int n = n0 + nh*64 + rowN;
        int hH = n >> 6, d = n & 63;
        *(int4*)(Vt + ((size_t)((bB<<4) + hH)*64 + d)*2048 + t0 + ch*8) = v;
      }
    }
    return;
  }

  // Q/K: stage [m][n] tile half-by-half in LDS (stride 72), then coalesced int4 row stores
  short* dst = (z == 0) ? Qo : Ko;
#pragma unroll
  for (int nh = 0; nh < 2; ++nh){
    __syncthreads();
    if (wn == nh){
#pragma unroll
      for (int nt = 0; nt < 4; ++nt){
        int n_l = nt*16 + lr;
        float bv = bias[n0 + nh*64 + n_l];
#pragma unroll
        for (int mt = 0; mt < 4; ++mt){
#pragma unroll
          for (int r = 0; r < 4; ++r){
            int m_l = wm*64 + mt*16 + quad*4 + r;
            float v = acc[mt][nt][r] + bv;
            if (z == 0) v *= qscale;
            smem[m_l*72 + n_l] = f2bf(v);
          }
        }
      }
    }
    __syncthreads();
    const int hH = (n0 + nh*64) >> 6;
    short* dhead = dst + (size_t)((bB<<4) + hH) * 2048 * 64;
#pragma unroll
    for (int i = 0; i < 4; ++i){
      int c = tid + i*256;
      int rowm = c >> 3, ch = (c & 7) << 3;
      int4 v = *(const int4*)(smem + rowm*72 + ch);
      *(int4*)(dhead + (size_t)(t0 + rowm)*64 + ch) = v;
    }
  }
}

// ---------------- output projection: 128x128 tiles, K-split=2 -> fp32 partials ----------------
// R5 budget analysis: old 128x64-tile proj was ~41 us (210 TF) — latency-bound at 8 waves/CU with
// low MFMA density (3000 cyc/kt-unit for half of qkv's per-kt work). Now: full qkv-density
// 128x128 tiles, K halved per block (8 kt), grid (8,32,2) = 512 blocks = 2/CU. Per-CU kt-units:
// 2x8=16 (was 32 at lower density). Partials are exact fp32 sums; combine adds halves + bias.
__launch_bounds__(256, 3)
__global__ void gemm_proj(const short* __restrict__ A, const short* __restrict__ Wm,
                          float* __restrict__ Pp)
{
  __shared__ __align__(16) short smem[16384];
  const int tid = threadIdx.x;
  const int lane = tid & 63, wave = tid >> 6;
  const int wm = wave >> 1, wn = wave & 1;
  const int quad = lane >> 4, lr = lane & 15;
  const int m0 = blockIdx.y * 128, n0 = blockIdx.x * 128;
  const int k0 = blockIdx.z * 512;

  f32x4 acc[4][4];
#pragma unroll
  for (int i = 0; i < 4; ++i)
#pragma unroll
    for (int j = 0; j < 4; ++j)
#pragma unroll
      for (int r = 0; r < 4; ++r) acc[i][j][r] = 0.f;

  gemm_core(A, Wm, smem, smem + 8192, m0, n0, k0, 8, tid, wm, wn, quad, lr, acc);

  float* Op = Pp + (size_t)blockIdx.z * 4194304;   // [2][4096][1024] f32
#pragma unroll
  for (int nt = 0; nt < 4; ++nt){
    int n = n0 + wn*64 + nt*16 + lr;
#pragma unroll
    for (int mt = 0; mt < 4; ++mt){
      int mBase = m0 + wm*64 + mt*16 + quad*4;
#pragma unroll
      for (int r = 0; r < 4; ++r)
        Op[(size_t)(mBase + r) * 1024 + n] = acc[mt][nt][r];
    }
  }
}

// out = P0 + P1 + bias ; 4096x1024 f32, f32x4 per thread
__global__ void proj_combine(const float* __restrict__ Pp, const float* __restrict__ bias,
                             float* __restrict__ out)
{
  const int gid = blockIdx.x * 256 + threadIdx.x;   // 1048576 quads
  const f32x4 a = *(const f32x4*)(Pp + (size_t)gid * 4);
  const f32x4 b = *(const f32x4*)(Pp + 4194304 + (size_t)gid * 4);
  const f32x4 bv = *(const f32x4*)(bias + ((gid << 2) & 1023));
  f32x4 o;
#pragma unroll
  for (int r = 0; r < 4; ++r) o[r] = a[r] + b[r] + bv[r];
  *(f32x4*)(out + (size_t)gid * 4) = o;
}

// ---------------- flash attention (causal): 128-row bands, 32 q/wave, 3 blocks/CU ----------------
// Q (pre-scaled by log2e/8), K: [B*H, T, 64] bf16 ; Vt: [B*H, 64, T] bf16 ; AO: [B*T, 1024] bf16
// Verified R4 schedule: 3 co-resident tasks per CU run in PARALLEL; per-CU sum = 34 steps with
// mixed lengths. Bands qb>=8 KV-split into exact-additive halves; combine normalizes t>=1024.
// slice_tbl entry: (qb<<11) | (kv_start<<6) | kv_len ; row a = CU slice, col j = dispatch wave.
__device__ __constant__ int slice_tbl[24] = {
  14352, 30736,     2,   // a=0: U7(16),  Ha15(16), U0(2)
  31760, 26638,  2052,   // a=1: Hb15(16), Ha13(14), U1(4)
  12302, 27534,  4102,   // a=2: U6(14),  Hb13(14), U2(6)
  28687, 20491,  6152,   // a=3: Ha14(15), Ha10(11), U3(8)
  29647, 19082, 16393,   // a=4: Hb14(15), Hb9(10),  Ha8(9)
  24589, 10252, 16969,   // a=5: Ha12(13), U5(12),  Hb8(9)
  25421, 21195,  8202,   // a=6: Hb12(13), Hb10(11), U4(10)
  22540, 23308, 18442    // a=7: Ha11(12), Hb11(12), Ha9(10)
};

__launch_bounds__(256, 3)
__global__ void attn_kernel(const short* __restrict__ Q, const short* __restrict__ K,
                            const short* __restrict__ Vt, short* __restrict__ AO,
                            float* __restrict__ Opart, float* __restrict__ Lpart)
{
  __shared__ __align__(16) short Ks[2][4096];   // [buf][64 rows x 64 shorts], swizzled
  __shared__ __align__(16) short Vs[2][4096];
  __shared__ __align__(16) short Ps[8192];      // per-wave 2x(16x64) P^T/O^T scratch, swizzled
  const int tid = threadIdx.x, lane = tid & 63, wave = tid >> 6;
  const int quad = lane >> 4, lr = lane & 15;
  const int bid = blockIdx.x;
  const int a = (bid >> 5) & 7;                // CU slice
  const int hb = bid & 31;
  const int j = bid >> 8;                      // dispatch wave 0..2 (j*256 apart -> same CU)
  const int e = slice_tbl[a*3 + j];
  const int qb = e >> 11, kv_s = (e >> 6) & 31, kvn = e & 63;
  const bool split = (kvn != 2*qb + 2);
  const int half = (kv_s != 0) ? 1 : 0;
  const int bidx = hb >> 4, h = hb & 15;
  const int wq0 = qb * 128 + wave * 32;        // this wave's 32 q-rows (two 16-row groups)
  const short* Qh = Q  + (size_t)hb * TT * 64;
  const short* Kh = K  + (size_t)hb * TT * 64;
  const short* Vh = Vt + (size_t)hb * 64 * TT;
  short* Pw = Ps + wave * 2048;                // two 1024-short regions (one per q-group)

  // staging: chunk c = tid covers (row = c>>3, swizzled col-chunk); c+256 = row+32, same swizzle
  const int srow = tid >> 3;
  const int ssw  = (tid & 7) ^ (srow & 7);
  const short* Kp0 = Kh + (size_t)srow * 64 + ssw * 8;
  const short* Vp0 = Vh + (size_t)srow * TT + ssw * 8;

  // loop-invariant Q fragments (B-operand: n = lr = q), one pair per q-group
  bf16x8 qf[2][2];
#pragma unroll
  for (int g = 0; g < 2; ++g)
#pragma unroll
    for (int ks = 0; ks < 2; ++ks)
      qf[g][ks] = *(const bf16x8*)(Qh + (size_t)(wq0 + g*16 + lr) * 64 + ks*32 + quad*8);

  // swizzled frag-read chunk offsets (loop-invariant): chunk ks*4+quad, row-phase lr&7
  const int lsw0 = (((0*4 + quad) ^ (lr & 7)) << 3);
  const int lsw1 = (((1*4 + quad) ^ (lr & 7)) << 3);
  const int qh2 = quad >> 1, qlo = (quad & 1) << 2;

  f32x4 acc_o[2][4], l_acc[2];
#pragma unroll
  for (int g = 0; g < 2; ++g){
#pragma unroll
    for (int r = 0; r < 4; ++r) l_acc[g][r] = 0.f;
#pragma unroll
    for (int dt = 0; dt < 4; ++dt)
#pragma unroll
      for (int r = 0; r < 4; ++r) acc_o[g][dt][r] = 0.f;
  }

  const short one_bf = (short)0x3F80;
  const bf16x8 onesf = { one_bf, one_bf, one_bf, one_bf, one_bf, one_bf, one_bf, one_bf };

  const int kv_e = kv_s + kvn;
  const int qtw = wq0 >> 6;                    // wave's diagonal KV-tile (both q-groups share it)
  // prologue: stage tile kv_s into buffer 0 (async)
  {
    const short* kp = Kp0 + (size_t)kv_s * 4096;
    const short* vp = Vp0 + kv_s * 64;
    async16(kp,          &Ks[0][(size_t)tid * 8]);
    async16(kp + 32*64,  &Ks[0][(size_t)(tid + 256) * 8]);
    async16(vp,          &Vs[0][(size_t)tid * 8]);
    async16(vp + 32*TT,  &Vs[0][(size_t)(tid + 256) * 8]);
  }

  // strength-reduced next-tile staging pointers
  const short* kp_n = Kp0 + (size_t)(kv_s + 1) * 4096;
  const short* vp_n = Vp0 + (kv_s + 1) * 64;

  int cur = 0;
  for (int kv = kv_s; kv < kv_e; ++kv){
    const int kv0 = kv * 64;
    __syncthreads();                     // drains vmcnt: buf[cur] ready; prior reads of buf[cur^1] done
    if (kv + 1 < kv_e){                  // async stage tile kv+1 into the other buffer
      const int nb = cur ^ 1;
      async16(kp_n,          &Ks[nb][(size_t)tid * 8]);
      async16(kp_n + 32*64,  &Ks[nb][(size_t)(tid + 256) * 8]);
      async16(vp_n,          &Vs[nb][(size_t)tid * 8]);
      async16(vp_n + 32*TT,  &Vs[nb][(size_t)(tid + 256) * 8]);
      kp_n += 4096; vp_n += 64;
    }
    if (kv0 <= wq0 + 31){
      // S^T = K Q^T for both q-groups; each kf fragment read once, used twice
      f32x4 s4[2][4];
#pragma unroll
      for (int g = 0; g < 2; ++g)
#pragma unroll
        for (int nt = 0; nt < 4; ++nt)
#pragma unroll
          for (int r = 0; r < 4; ++r) s4[g][nt][r] = 0.f;
#pragma unroll
      for (int nt = 0; nt < 4; ++nt){
        bf16x8 kf0 = *(const bf16x8*)(&Ks[cur][(nt*16 + lr)*64 + lsw0]);
        bf16x8 kf1 = *(const bf16x8*)(&Ks[cur][(nt*16 + lr)*64 + lsw1]);
#pragma unroll
        for (int g = 0; g < 2; ++g){
          s4[g][nt] = __builtin_amdgcn_mfma_f32_16x16x32_bf16(kf0, qf[g][0], s4[g][nt], 0, 0, 0);
          s4[g][nt] = __builtin_amdgcn_mfma_f32_16x16x32_bf16(kf1, qf[g][1], s4[g][nt], 0, 0, 0);
        }
      }

      // P^T = exp2(S^T); diagonal-tile masking hoisted into a wave-uniform branch
      if (kv == qtw){
#pragma unroll
        for (int g = 0; g < 2; ++g){
          const int qglob = wq0 + g*16 + lr;
          short* Pg = Pw + g*1024;
#pragma unroll
          for (int nt = 0; nt < 4; ++nt){
            const int keyb = kv0 + nt*16 + quad*4;
            float pv[4];
#pragma unroll
            for (int r = 0; r < 4; ++r){
              float v = exp2f(s4[g][nt][r]);
              if (keyb + r > qglob) v = 0.f;
              pv[r] = v;
            }
            int2 w;
            w.x = pk2bf(pv[0], pv[1]);
            w.y = pk2bf(pv[2], pv[3]);
            const int gg = nt*2 + qh2;
            *(int2*)(Pg + lr*64 + ((gg ^ (lr & 7)) << 3) + qlo) = w;
          }
        }
      } else {
#pragma unroll
        for (int g = 0; g < 2; ++g){
          short* Pg = Pw + g*1024;
#pragma unroll
          for (int nt = 0; nt < 4; ++nt){
            int2 w;
            w.x = pk2bf(exp2f(s4[g][nt][0]), exp2f(s4[g][nt][1]));
            w.y = pk2bf(exp2f(s4[g][nt][2]), exp2f(s4[g][nt][3]));
            const int gg = nt*2 + qh2;
            *(int2*)(Pg + lr*64 + ((gg ^ (lr & 7)) << 3) + qlo) = w;
          }
        }
      }
      // wave-private Pw: lgkmcnt ordering only, no barrier

      // l += 1^T P^T ; O^T += V^T P^T ; each vf fragment read once, used twice
#pragma unroll
      for (int ks = 0; ks < 2; ++ks){
        const int lsw = ks ? lsw1 : lsw0;
        bf16x8 ptf0 = *(const bf16x8*)(Pw + lr*64 + lsw);
        bf16x8 ptf1 = *(const bf16x8*)(Pw + 1024 + lr*64 + lsw);
        l_acc[0] = __builtin_amdgcn_mfma_f32_16x16x32_bf16(onesf, ptf0, l_acc[0], 0, 0, 0);
        l_acc[1] = __builtin_amdgcn_mfma_f32_16x16x32_bf16(onesf, ptf1, l_acc[1], 0, 0, 0);
#pragma unroll
        for (int dt = 0; dt < 4; ++dt){
          bf16x8 vf = *(const bf16x8*)(&Vs[cur][(dt*16 + lr)*64 + lsw]);
          acc_o[0][dt] = __builtin_amdgcn_mfma_f32_16x16x32_bf16(vf, ptf0, acc_o[0][dt], 0, 0, 0);
          acc_o[1][dt] = __builtin_amdgcn_mfma_f32_16x16x32_bf16(vf, ptf1, acc_o[1][dt], 0, 0, 0);
        }
      }
    }
    cur ^= 1;
  }

  if (split){
    // partial epilogue: raw fp32 O + l to workspace; exact additive combine later (no max-rescale)
    const int p = (((hb << 3) | (qb - 8)) << 1) + half;
    float* Op = Opart + (size_t)p * 8192;     // [128 q][64 d] f32
#pragma unroll
    for (int g = 0; g < 2; ++g){
      const int q_l = wave*32 + g*16 + lr;
#pragma unroll
      for (int dt = 0; dt < 4; ++dt)
        *(f32x4*)(Op + q_l*64 + dt*16 + quad*4) = acc_o[g][dt];
      if (lane < 16) Lpart[p*128 + wave*32 + g*16 + lane] = l_acc[g][0];
    }
    return;
  }

  // epilogue (unsplit): O = O^T / l per q-group; transpose via swizzled wave-private LDS -> int4 stores
#pragma unroll
  for (int g = 0; g < 2; ++g){
    short* Pg = Pw + g*1024;
    const float inv = __builtin_amdgcn_rcpf(l_acc[g][0]);   // all regs equal l[q=lr]
#pragma unroll
    for (int dt = 0; dt < 4; ++dt){
      int2 w;
      w.x = pk2bf(acc_o[g][dt][0] * inv, acc_o[g][dt][1] * inv);
      w.y = pk2bf(acc_o[g][dt][2] * inv, acc_o[g][dt][3] * inv);
      const int gg = dt*2 + qh2;
      *(int2*)(Pg + lr*64 + ((gg ^ (lr & 7)) << 3) + qlo) = w;
    }
    // wave-private: compiler inserts lgkmcnt wait before the reads below
#pragma unroll
    for (int i = 0; i < 2; ++i){
      int c = lane + i*64;               // 128 chunks: 16 q-rows x 8 chunks of 8 shorts
      int row = c >> 3, ch = c & 7;
      int4 v = *(const int4*)(Pg + row*64 + ((ch ^ (row & 7)) << 3));
      *(int4*)(AO + (size_t)(bidx*2048 + wq0 + g*16 + row)*1024 + h*64 + ch*8) = v;
    }
  }
}

// ---------------- combine: O = (O0+O1)/(l0+l1) for split bands (t >= 1024 per batch) ----------------
__global__ void attn_combine(const float* __restrict__ Opart, const float* __restrict__ Lpart,
                             short* __restrict__ AO)
{
  const int gid = blockIdx.x * 256 + threadIdx.x;  // 524288 = 32768 rows x 16 d-quads
  const int row = gid >> 4, dq = (gid & 15) << 2;
  const int hb = row >> 10, band = (row >> 7) & 7, r = row & 127;
  const int p = ((hb << 3) | band) << 1;
  const f32x4 a = *(const f32x4*)(Opart + (size_t)p*8192 + r*64 + dq);
  const f32x4 b = *(const f32x4*)(Opart + (size_t)(p+1)*8192 + r*64 + dq);
  const float l = Lpart[p*128 + r] + Lpart[(p+1)*128 + r];
  const float inv = __builtin_amdgcn_rcpf(l);
  int2 w;
  w.x = pk2bf((a[0]+b[0])*inv, (a[1]+b[1])*inv);
  w.y = pk2bf((a[2]+b[2])*inv, (a[3]+b[3])*inv);
  const int t = (8 + band)*128 + r;
  const int bidx = hb >> 4, h = hb & 15;
  *(int2*)(AO + (size_t)(bidx*2048 + t)*1024 + h*64 + dq) = w;
}

extern "C" void kernel_launch(void* const* d_in, const int* in_sizes, int n_in,
                              void* d_out, int out_size, void* d_ws, size_t ws_size,
                              hipStream_t stream)
{
  const float* x  = (const float*)d_in[0];
  const float* Wq = (const float*)d_in[1];
  const float* bq = (const float*)d_in[2];
  const float* Wk = (const float*)d_in[3];
  const float* bk = (const float*)d_in[4];
  const float* Wv = (const float*)d_in[5];
  const float* bv = (const float*)d_in[6];
  const float* Wp = (const float*)d_in[7];
  const float* bp = (const float*)d_in[8];
  float* out = (float*)d_out;

  char* ws = (char*)d_ws;
  const size_t MB = 1024ull * 1024ull;
  short* Qb  = (short*)(ws + 0);        // [B,H,T,D] bf16 (pre-scaled by log2e/8)
  short* Kb  = (short*)(ws + 8*MB);     // [B,H,T,D] bf16
  short* Vtb = (short*)(ws + 16*MB);    // [B,H,D,T] bf16
  short* AOb = (short*)(ws + 24*MB);    // [B*T, C] bf16 — aliases xb (qkv reads finish first)
  short* xb  = (short*)(ws + 24*MB);    // [M, C] bf16
  short* Wqb = (short*)(ws + 32*MB);
  short* Wkb = (short*)(ws + 34*MB);
  short* Wvb = (short*)(ws + 36*MB);
  short* Wpb = (short*)(ws + 38*MB);
  float* Opart = (float*)(ws + 40*MB);  // 512 x 128x64 f32 partial O (16 MB)
  float* Lpart = (float*)(ws + 56*MB);  // 512 x 128 f32 partial l (256 KB)
  float* Pproj = (float*)(ws + 64*MB);  // 2 x 4096x1024 f32 proj partials (32 MB)

  cvt_all<<<8192, 256, 0, stream>>>(x, Wq, Wk, Wv, Wp, xb, Wqb, Wkb, Wvb, Wpb);
  gemm_qkv<<<dim3(8, 32, 3), 256, 0, stream>>>(xb, Wqb, Wkb, Wvb, bq, bk, bv, Qb, Kb, Vtb);
  attn_kernel<<<768, 256, 0, stream>>>(Qb, Kb, Vtb, AOb, Opart, Lpart);
  attn_combine<<<2048, 256, 0, stream>>>(Opart, Lpart, AOb);
  gemm_proj<<<dim3(8, 32, 2), 256, 0, stream>>>(AOb, Wpb, Pproj);
  proj_combine<<<4096, 256, 0, stream>>>(Pproj, bp, out);
}

// Round 8
// 180.892 us; speedup vs baseline: 1.1181x; 1.0425x over previous
//
#include <hip/hip_runtime.h>
#include <hip/hip_bf16.h>

// B=2, T=2048, C=1024, H=16, D=64, M = B*T = 4096
#define TT 2048
#define MM 4096

typedef __attribute__((ext_vector_type(8))) short bf16x8;
typedef __attribute__((ext_vector_type(4))) float f32x4;

__device__ inline short f2bf(float f){
  union { float f; unsigned u; } x; x.f = f;
  unsigned r = x.u + 0x7FFFu + ((x.u >> 16) & 1u);
  return (short)(r >> 16);
}
__device__ inline int pk2bf(float a, float b){
  __hip_bfloat162 h2 = __float22bfloat162_rn(make_float2(a, b));
  return *(int*)&h2;
}

// async global->LDS, 16B per lane; LDS dest must be wave-uniform base + lane*16
__device__ inline void async16(const void* g, void* l){
  __builtin_amdgcn_global_load_lds((const __attribute__((address_space(1))) void*)g,
                                   (__attribute__((address_space(3))) void*)l, 16, 0, 0);
}

// ---------------- fused fp32 -> bf16 convert (x + 4 weights, one launch) ----------------
__global__ void cvt_all(const float* __restrict__ x,
                        const float* __restrict__ Wq, const float* __restrict__ Wk,
                        const float* __restrict__ Wv, const float* __restrict__ Wp,
                        short* __restrict__ xb, short* __restrict__ Wqb, short* __restrict__ Wkb,
                        short* __restrict__ Wvb, short* __restrict__ Wpb){
  int b = blockIdx.x;
  const float* in; short* out; int base;
  if (b < 4096)      { in = x;  out = xb;  base = b; }
  else if (b < 5120) { in = Wq; out = Wqb; base = b - 4096; }
  else if (b < 6144) { in = Wk; out = Wkb; base = b - 5120; }
  else if (b < 7168) { in = Wv; out = Wvb; base = b - 6144; }
  else               { in = Wp; out = Wpb; base = b - 7168; }
  int i = base * 256 + threadIdx.x;
  float4 v = ((const float4*)in)[i];
  short4 o;
  o.x = f2bf(v.x); o.y = f2bf(v.y); o.z = f2bf(v.z); o.w = f2bf(v.w);
  ((short4*)out)[i] = o;
}

// ---------------- GEMM core: 128x128 tile, BK=64 as two BK=32 panels, two-barrier (proven) ----------------
__device__ inline void gemm_core(const short* __restrict__ A, const short* __restrict__ Wm,
                                 short* As, short* Bs, int m0, int n0, int k0, int nkt,
                                 int tid, int wm, int wn, int quad, int lr,
                                 f32x4 acc[4][4])
{
  const int prow = tid >> 2, pcol = (tid & 3) << 3;
  const short* Ap0 = A  + (size_t)(m0 + prow) * 1024 + k0 + pcol;
  const short* Ap1 = Ap0 + 64 * 1024;
  const short* Bp0 = Wm + (size_t)(n0 + prow) * 1024 + k0 + pcol;
  const short* Bp1 = Bp0 + 64 * 1024;
  for (int kt = 0; kt < nkt; ++kt){
    const int kk = kt * 64;
#pragma unroll
    for (int pn = 0; pn < 2; ++pn){
      async16(Ap0 + kk + pn*32, As + pn*4096 + (size_t)tid * 8);
      async16(Ap1 + kk + pn*32, As + pn*4096 + (size_t)(tid + 256) * 8);
      async16(Bp0 + kk + pn*32, Bs + pn*4096 + (size_t)tid * 8);
      async16(Bp1 + kk + pn*32, Bs + pn*4096 + (size_t)(tid + 256) * 8);
    }
    __syncthreads();
#pragma unroll
    for (int ks = 0; ks < 2; ++ks){
      bf16x8 aF[4], bF[4];
#pragma unroll
      for (int mt = 0; mt < 4; ++mt) aF[mt] = *(const bf16x8*)(As + ks*4096 + (wm*64 + mt*16 + lr)*32 + quad*8);
#pragma unroll
      for (int nt = 0; nt < 4; ++nt) bF[nt] = *(const bf16x8*)(Bs + ks*4096 + (wn*64 + nt*16 + lr)*32 + quad*8);
#pragma unroll
      for (int mt = 0; mt < 4; ++mt)
#pragma unroll
        for (int nt = 0; nt < 4; ++nt)
          acc[mt][nt] = __builtin_amdgcn_mfma_f32_16x16x32_bf16(aF[mt], bF[nt], acc[mt][nt], 0, 0, 0);
    }
    __syncthreads();
  }
}

// ---------------- QKV projection: Q,K as [B,H,T,D] (Q pre-scaled), V as [B,H,D,T] ----------------
// R6 diagnosis: FETCH_SIZE 68.7MB vs 14MB ideal — same-XCD blocks (linear id = n + 8m + 256z,
// round-robin XCD) share n but stream ALL 32 A-panels (8MB >> 4MB L2): A re-fetched ~8x.
// Fix (T1, m-grouped): each XCD owns 4 contiguous m-panels (A 1MB resident) x all 8 n (W 2MB
// resident per z). Bijective remap of (xcd = bid&7, slot = bid>>3) -> (z, m, n).
__launch_bounds__(256, 3)
__global__ void gemm_qkv(const short* __restrict__ A,
                         const short* __restrict__ W0, const short* __restrict__ W1, const short* __restrict__ W2,
                         const float* __restrict__ b0, const float* __restrict__ b1, const float* __restrict__ b2,
                         short* __restrict__ Qo, short* __restrict__ Ko, short* __restrict__ Vt)
{
  __shared__ __align__(16) short smem[16384];
  short* As = smem;
  short* Bs = smem + 8192;
  const int bid = blockIdx.x + (blockIdx.y << 3) + (blockIdx.z << 8);
  const int xcd = bid & 7, slot = bid >> 3;
  const int z   = slot >> 5;                       // 0..2
  const int rem = slot & 31;                       // 4 m-panels x 8 n-panels
  const int m0  = (((xcd << 2) + (rem >> 3))) * 128;
  const int n0  = (rem & 7) * 128;
  const short* Wm   = (z == 0) ? W0 : ((z == 1) ? W1 : W2);
  const float* bias = (z == 0) ? b0 : ((z == 1) ? b1 : b2);
  const int tid = threadIdx.x;
  const int lane = tid & 63, wave = tid >> 6;
  const int wm = wave >> 1, wn = wave & 1;
  const int quad = lane >> 4, lr = lane & 15;

  f32x4 acc[4][4];
#pragma unroll
  for (int i = 0; i < 4; ++i)
#pragma unroll
    for (int j = 0; j < 4; ++j)
#pragma unroll
      for (int r = 0; r < 4; ++r) acc[i][j][r] = 0.f;

  gemm_core(A, Wm, As, Bs, m0, n0, 0, 16, tid, wm, wn, quad, lr, acc);

  const float qscale = 0.125f * 1.4426950408889634f;  // scale/sqrt(D) * log2(e) folded into Q
  const int bB = m0 >> 11, t0 = m0 & 2047;

  if (z == 2){
    // V: transpose in LDS -> coalesced [B,H,D,T] stores
#pragma unroll
    for (int nh = 0; nh < 2; ++nh){
      __syncthreads();
      if (wn == nh){
#pragma unroll
        for (int nt = 0; nt < 4; ++nt){
          int n = n0 + wn*64 + nt*16 + lr;
          float bv = bias[n];
          int n_l = nt*16 + lr;
#pragma unroll
          for (int mt = 0; mt < 4; ++mt)
#pragma unroll
            for (int r = 0; r < 4; ++r){
              int m_l = wm*64 + mt*16 + quad*4 + r;
              smem[n_l*136 + m_l] = f2bf(acc[mt][nt][r] + bv);
            }
        }
      }
      __syncthreads();
#pragma unroll
      for (int i = 0; i < 4; ++i){
        int c = tid + i*256;
        int rowN = c >> 4, ch = c & 15;
        int4 v = *(const int4*)(smem + rowN*136 + ch*8);
        int n = n0 + nh*64 + rowN;
        int hH = n >> 6, d = n & 63;
        *(int4*)(Vt + ((size_t)((bB<<4) + hH)*64 + d)*2048 + t0 + ch*8) = v;
      }
    }
    return;
  }

  // Q/K: stage [m][n] tile half-by-half in LDS (stride 72), then coalesced int4 row stores
  short* dst = (z == 0) ? Qo : Ko;
#pragma unroll
  for (int nh = 0; nh < 2; ++nh){
    __syncthreads();
    if (wn == nh){
#pragma unroll
      for (int nt = 0; nt < 4; ++nt){
        int n_l = nt*16 + lr;
        float bv = bias[n0 + nh*64 + n_l];
#pragma unroll
        for (int mt = 0; mt < 4; ++mt){
#pragma unroll
          for (int r = 0; r < 4; ++r){
            int m_l = wm*64 + mt*16 + quad*4 + r;
            float v = acc[mt][nt][r] + bv;
            if (z == 0) v *= qscale;
            smem[m_l*72 + n_l] = f2bf(v);
          }
        }
      }
    }
    __syncthreads();
    const int hH = (n0 + nh*64) >> 6;
    short* dhead = dst + (size_t)((bB<<4) + hH) * 2048 * 64;
#pragma unroll
    for (int i = 0; i < 4; ++i){
      int c = tid + i*256;
      int rowm = c >> 3, ch = (c & 7) << 3;
      int4 v = *(const int4*)(smem + rowm*72 + ch);
      *(int4*)(dhead + (size_t)(t0 + rowm)*64 + ch) = v;
    }
  }
}

// ---------------- output projection: 128x64 tiles, BK=64 two-panel (R0 form) + XCD swizzle ----------------
// R6 post-mortem: K-split + combine was a wash (combine ate the gain). Revert to the proven
// direct structure; apply the same m-grouped XCD swizzle (A 1MB + W 2MB resident per XCD L2).
__launch_bounds__(256, 2)
__global__ void gemm_proj(const short* __restrict__ A, const short* __restrict__ Wm,
                          const float* __restrict__ bias, float* __restrict__ out)
{
  __shared__ __align__(16) short As[2*4096];
  __shared__ __align__(16) short Bs[2*2048];
  const int bid = blockIdx.x + (blockIdx.y << 4);
  const int xcd = bid & 7, slot = bid >> 3;        // slot in [0,64): 4 m x 16 n
  const int m0  = ((xcd << 2) + (slot >> 4)) * 128;
  const int n0  = (slot & 15) * 64;
  const int tid = threadIdx.x;
  const int lane = tid & 63, wave = tid >> 6;
  const int quad = lane >> 4, lr = lane & 15;

  const int prow = tid >> 2, pcol = (tid & 3) << 3;
  const short* Ap0 = A  + (size_t)(m0 + prow) * 1024 + pcol;
  const short* Ap1 = Ap0 + 64 * 1024;
  const short* Bp0 = Wm + (size_t)(n0 + prow) * 1024 + pcol;

  f32x4 acc[2][4];
#pragma unroll
  for (int i = 0; i < 2; ++i)
#pragma unroll
    for (int j = 0; j < 4; ++j)
#pragma unroll
      for (int r = 0; r < 4; ++r) acc[i][j][r] = 0.f;

  for (int kt = 0; kt < 16; ++kt){
    const int kk = kt * 64;
#pragma unroll
    for (int pn = 0; pn < 2; ++pn){
      async16(Ap0 + kk + pn*32, As + pn*4096 + (size_t)tid * 8);
      async16(Ap1 + kk + pn*32, As + pn*4096 + (size_t)(tid + 256) * 8);
      async16(Bp0 + kk + pn*32, Bs + pn*2048 + (size_t)tid * 8);
    }
    __syncthreads();
#pragma unroll
    for (int ks = 0; ks < 2; ++ks){
      bf16x8 aF[2], bF[4];
#pragma unroll
      for (int mt = 0; mt < 2; ++mt) aF[mt] = *(const bf16x8*)(As + ks*4096 + (wave*32 + mt*16 + lr)*32 + quad*8);
#pragma unroll
      for (int nt = 0; nt < 4; ++nt) bF[nt] = *(const bf16x8*)(Bs + ks*2048 + (nt*16 + lr)*32 + quad*8);
#pragma unroll
      for (int mt = 0; mt < 2; ++mt)
#pragma unroll
        for (int nt = 0; nt < 4; ++nt)
          acc[mt][nt] = __builtin_amdgcn_mfma_f32_16x16x32_bf16(aF[mt], bF[nt], acc[mt][nt], 0, 0, 0);
    }
    __syncthreads();
  }

#pragma unroll
  for (int nt = 0; nt < 4; ++nt){
    int n = n0 + nt*16 + lr;
    float bv = bias[n];
#pragma unroll
    for (int mt = 0; mt < 2; ++mt){
      int mBase = m0 + wave*32 + mt*16 + quad*4;
#pragma unroll
      for (int r = 0; r < 4; ++r){
        int m = mBase + r;
        out[(size_t)m * 1024 + n] = acc[mt][nt][r] + bv;
      }
    }
  }
}

// ---------------- flash attention (causal): 128-row bands, 32 q/wave, 3 blocks/CU ----------------
// Q (pre-scaled by log2e/8), K: [B*H, T, 64] bf16 ; Vt: [B*H, 64, T] bf16 ; AO: [B*T, 1024] bf16
// Verified R4 schedule: 3 co-resident tasks per CU run in PARALLEL; per-CU sum = 34 steps with
// mixed lengths. Bands qb>=8 KV-split into exact-additive halves; combine normalizes t>=1024.
// slice_tbl entry: (qb<<11) | (kv_start<<6) | kv_len ; row a = CU slice, col j = dispatch wave.
__device__ __constant__ int slice_tbl[24] = {
  14352, 30736,     2,   // a=0: U7(16),  Ha15(16), U0(2)
  31760, 26638,  2052,   // a=1: Hb15(16), Ha13(14), U1(4)
  12302, 27534,  4102,   // a=2: U6(14),  Hb13(14), U2(6)
  28687, 20491,  6152,   // a=3: Ha14(15), Ha10(11), U3(8)
  29647, 19082, 16393,   // a=4: Hb14(15), Hb9(10),  Ha8(9)
  24589, 10252, 16969,   // a=5: Ha12(13), U5(12),  Hb8(9)
  25421, 21195,  8202,   // a=6: Hb12(13), Hb10(11), U4(10)
  22540, 23308, 18442    // a=7: Ha11(12), Hb11(12), Ha9(10)
};

__launch_bounds__(256, 3)
__global__ void attn_kernel(const short* __restrict__ Q, const short* __restrict__ K,
                            const short* __restrict__ Vt, short* __restrict__ AO,
                            float* __restrict__ Opart, float* __restrict__ Lpart)
{
  __shared__ __align__(16) short Ks[2][4096];   // [buf][64 rows x 64 shorts], swizzled
  __shared__ __align__(16) short Vs[2][4096];
  __shared__ __align__(16) short Ps[8192];      // per-wave 2x(16x64) P^T/O^T scratch, swizzled
  const int tid = threadIdx.x, lane = tid & 63, wave = tid >> 6;
  const int quad = lane >> 4, lr = lane & 15;
  const int bid = blockIdx.x;
  const int a = (bid >> 5) & 7;                // CU slice
  const int hb = bid & 31;
  const int j = bid >> 8;                      // dispatch wave 0..2 (j*256 apart -> same CU)
  const int e = slice_tbl[a*3 + j];
  const int qb = e >> 11, kv_s = (e >> 6) & 31, kvn = e & 63;
  const bool split = (kvn != 2*qb + 2);
  const int half = (kv_s != 0) ? 1 : 0;
  const int bidx = hb >> 4, h = hb & 15;
  const int wq0 = qb * 128 + wave * 32;        // this wave's 32 q-rows (two 16-row groups)
  const short* Qh = Q  + (size_t)hb * TT * 64;
  const short* Kh = K  + (size_t)hb * TT * 64;
  const short* Vh = Vt + (size_t)hb * 64 * TT;
  short* Pw = Ps + wave * 2048;                // two 1024-short regions (one per q-group)

  // staging: chunk c = tid covers (row = c>>3, swizzled col-chunk); c+256 = row+32, same swizzle
  const int srow = tid >> 3;
  const int ssw  = (tid & 7) ^ (srow & 7);
  const short* Kp0 = Kh + (size_t)srow * 64 + ssw * 8;
  const short* Vp0 = Vh + (size_t)srow * TT + ssw * 8;

  // loop-invariant Q fragments (B-operand: n = lr = q), one pair per q-group
  bf16x8 qf[2][2];
#pragma unroll
  for (int g = 0; g < 2; ++g)
#pragma unroll
    for (int ks = 0; ks < 2; ++ks)
      qf[g][ks] = *(const bf16x8*)(Qh + (size_t)(wq0 + g*16 + lr) * 64 + ks*32 + quad*8);

  // swizzled frag-read chunk offsets (loop-invariant): chunk ks*4+quad, row-phase lr&7
  const int lsw0 = (((0*4 + quad) ^ (lr & 7)) << 3);
  const int lsw1 = (((1*4 + quad) ^ (lr & 7)) << 3);
  const int qh2 = quad >> 1, qlo = (quad & 1) << 2;

  f32x4 acc_o[2][4], l_acc[2];
#pragma unroll
  for (int g = 0; g < 2; ++g){
#pragma unroll
    for (int r = 0; r < 4; ++r) l_acc[g][r] = 0.f;
#pragma unroll
    for (int dt = 0; dt < 4; ++dt)
#pragma unroll
      for (int r = 0; r < 4; ++r) acc_o[g][dt][r] = 0.f;
  }

  const short one_bf = (short)0x3F80;
  const bf16x8 onesf = { one_bf, one_bf, one_bf, one_bf, one_bf, one_bf, one_bf, one_bf };

  const int kv_e = kv_s + kvn;
  const int qtw = wq0 >> 6;                    // wave's diagonal KV-tile (both q-groups share it)
  // prologue: stage tile kv_s into buffer 0 (async)
  {
    const short* kp = Kp0 + (size_t)kv_s * 4096;
    const short* vp = Vp0 + kv_s * 64;
    async16(kp,          &Ks[0][(size_t)tid * 8]);
    async16(kp + 32*64,  &Ks[0][(size_t)(tid + 256) * 8]);
    async16(vp,          &Vs[0][(size_t)tid * 8]);
    async16(vp + 32*TT,  &Vs[0][(size_t)(tid + 256) * 8]);
  }

  // strength-reduced next-tile staging pointers
  const short* kp_n = Kp0 + (size_t)(kv_s + 1) * 4096;
  const short* vp_n = Vp0 + (kv_s + 1) * 64;

  int cur = 0;
  for (int kv = kv_s; kv < kv_e; ++kv){
    const int kv0 = kv * 64;
    __syncthreads();                     // drains vmcnt: buf[cur] ready; prior reads of buf[cur^1] done
    if (kv + 1 < kv_e){                  // async stage tile kv+1 into the other buffer
      const int nb = cur ^ 1;
      async16(kp_n,          &Ks[nb][(size_t)tid * 8]);
      async16(kp_n + 32*64,  &Ks[nb][(size_t)(tid + 256) * 8]);
      async16(vp_n,          &Vs[nb][(size_t)tid * 8]);
      async16(vp_n + 32*TT,  &Vs[nb][(size_t)(tid + 256) * 8]);
      kp_n += 4096; vp_n += 64;
    }
    if (kv0 <= wq0 + 31){
      __builtin_amdgcn_s_setprio(1);     // favor compute waves over co-resident stagers (m191)
      // S^T = K Q^T for both q-groups; each kf fragment read once, used twice
      f32x4 s4[2][4];
#pragma unroll
      for (int g = 0; g < 2; ++g)
#pragma unroll
        for (int nt = 0; nt < 4; ++nt)
#pragma unroll
          for (int r = 0; r < 4; ++r) s4[g][nt][r] = 0.f;
#pragma unroll
      for (int nt = 0; nt < 4; ++nt){
        bf16x8 kf0 = *(const bf16x8*)(&Ks[cur][(nt*16 + lr)*64 + lsw0]);
        bf16x8 kf1 = *(const bf16x8*)(&Ks[cur][(nt*16 + lr)*64 + lsw1]);
#pragma unroll
        for (int g = 0; g < 2; ++g){
          s4[g][nt] = __builtin_amdgcn_mfma_f32_16x16x32_bf16(kf0, qf[g][0], s4[g][nt], 0, 0, 0);
          s4[g][nt] = __builtin_amdgcn_mfma_f32_16x16x32_bf16(kf1, qf[g][1], s4[g][nt], 0, 0, 0);
        }
      }

      // P^T = exp2(S^T); diagonal-tile masking hoisted into a wave-uniform branch
      if (kv == qtw){
#pragma unroll
        for (int g = 0; g < 2; ++g){
          const int qglob = wq0 + g*16 + lr;
          short* Pg = Pw + g*1024;
#pragma unroll
          for (int nt = 0; nt < 4; ++nt){
            const int keyb = kv0 + nt*16 + quad*4;
            float pv[4];
#pragma unroll
            for (int r = 0; r < 4; ++r){
              float v = exp2f(s4[g][nt][r]);
              if (keyb + r > qglob) v = 0.f;
              pv[r] = v;
            }
            int2 w;
            w.x = pk2bf(pv[0], pv[1]);
            w.y = pk2bf(pv[2], pv[3]);
            const int gg = nt*2 + qh2;
            *(int2*)(Pg + lr*64 + ((gg ^ (lr & 7)) << 3) + qlo) = w;
          }
        }
      } else {
#pragma unroll
        for (int g = 0; g < 2; ++g){
          short* Pg = Pw + g*1024;
#pragma unroll
          for (int nt = 0; nt < 4; ++nt){
            int2 w;
            w.x = pk2bf(exp2f(s4[g][nt][0]), exp2f(s4[g][nt][1]));
            w.y = pk2bf(exp2f(s4[g][nt][2]), exp2f(s4[g][nt][3]));
            const int gg = nt*2 + qh2;
            *(int2*)(Pg + lr*64 + ((gg ^ (lr & 7)) << 3) + qlo) = w;
          }
        }
      }
      // wave-private Pw: lgkmcnt ordering only, no barrier

      // l += 1^T P^T ; O^T += V^T P^T ; each vf fragment read once, used twice
#pragma unroll
      for (int ks = 0; ks < 2; ++ks){
        const int lsw = ks ? lsw1 : lsw0;
        bf16x8 ptf0 = *(const bf16x8*)(Pw + lr*64 + lsw);
        bf16x8 ptf1 = *(const bf16x8*)(Pw + 1024 + lr*64 + lsw);
        l_acc[0] = __builtin_amdgcn_mfma_f32_16x16x32_bf16(onesf, ptf0, l_acc[0], 0, 0, 0);
        l_acc[1] = __builtin_amdgcn_mfma_f32_16x16x32_bf16(onesf, ptf1, l_acc[1], 0, 0, 0);
#pragma unroll
        for (int dt = 0; dt < 4; ++dt){
          bf16x8 vf = *(const bf16x8*)(&Vs[cur][(dt*16 + lr)*64 + lsw]);
          acc_o[0][dt] = __builtin_amdgcn_mfma_f32_16x16x32_bf16(vf, ptf0, acc_o[0][dt], 0, 0, 0);
          acc_o[1][dt] = __builtin_amdgcn_mfma_f32_16x16x32_bf16(vf, ptf1, acc_o[1][dt], 0, 0, 0);
        }
      }
      __builtin_amdgcn_s_setprio(0);
    }
    cur ^= 1;
  }

  if (split){
    // partial epilogue: raw fp32 O + l to workspace; exact additive combine later (no max-rescale)
    const int p = (((hb << 3) | (qb - 8)) << 1) + half;
    float* Op = Opart + (size_t)p * 8192;     // [128 q][64 d] f32
#pragma unroll
    for (int g = 0; g < 2; ++g){
      const int q_l = wave*32 + g*16 + lr;
#pragma unroll
      for (int dt = 0; dt < 4; ++dt)
        *(f32x4*)(Op + q_l*64 + dt*16 + quad*4) = acc_o[g][dt];
      if (lane < 16) Lpart[p*128 + wave*32 + g*16 + lane] = l_acc[g][0];
    }
    return;
  }

  // epilogue (unsplit): O = O^T / l per q-group; transpose via swizzled wave-private LDS -> int4 stores
#pragma unroll
  for (int g = 0; g < 2; ++g){
    short* Pg = Pw + g*1024;
    const float inv = __builtin_amdgcn_rcpf(l_acc[g][0]);   // all regs equal l[q=lr]
#pragma unroll
    for (int dt = 0; dt < 4; ++dt){
      int2 w;
      w.x = pk2bf(acc_o[g][dt][0] * inv, acc_o[g][dt][1] * inv);
      w.y = pk2bf(acc_o[g][dt][2] * inv, acc_o[g][dt][3] * inv);
      const int gg = dt*2 + qh2;
      *(int2*)(Pg + lr*64 + ((gg ^ (lr & 7)) << 3) + qlo) = w;
    }
    // wave-private: compiler inserts lgkmcnt wait before the reads below
#pragma unroll
    for (int i = 0; i < 2; ++i){
      int c = lane + i*64;               // 128 chunks: 16 q-rows x 8 chunks of 8 shorts
      int row = c >> 3, ch = c & 7;
      int4 v = *(const int4*)(Pg + row*64 + ((ch ^ (row & 7)) << 3));
      *(int4*)(AO + (size_t)(bidx*2048 + wq0 + g*16 + row)*1024 + h*64 + ch*8) = v;
    }
  }
}

// ---------------- combine: O = (O0+O1)/(l0+l1) for split bands (t >= 1024 per batch) ----------------
__global__ void attn_combine(const float* __restrict__ Opart, const float* __restrict__ Lpart,
                             short* __restrict__ AO)
{
  const int gid = blockIdx.x * 256 + threadIdx.x;  // 524288 = 32768 rows x 16 d-quads
  const int row = gid >> 4, dq = (gid & 15) << 2;
  const int hb = row >> 10, band = (row >> 7) & 7, r = row & 127;
  const int p = ((hb << 3) | band) << 1;
  const f32x4 a = *(const f32x4*)(Opart + (size_t)p*8192 + r*64 + dq);
  const f32x4 b = *(const f32x4*)(Opart + (size_t)(p+1)*8192 + r*64 + dq);
  const float l = Lpart[p*128 + r] + Lpart[(p+1)*128 + r];
  const float inv = __builtin_amdgcn_rcpf(l);
  int2 w;
  w.x = pk2bf((a[0]+b[0])*inv, (a[1]+b[1])*inv);
  w.y = pk2bf((a[2]+b[2])*inv, (a[3]+b[3])*inv);
  const int t = (8 + band)*128 + r;
  const int bidx = hb >> 4, h = hb & 15;
  *(int2*)(AO + (size_t)(bidx*2048 + t)*1024 + h*64 + dq) = w;
}

extern "C" void kernel_launch(void* const* d_in, const int* in_sizes, int n_in,
                              void* d_out, int out_size, void* d_ws, size_t ws_size,
                              hipStream_t stream)
{
  const float* x  = (const float*)d_in[0];
  const float* Wq = (const float*)d_in[1];
  const float* bq = (const float*)d_in[2];
  const float* Wk = (const float*)d_in[3];
  const float* bk = (const float*)d_in[4];
  const float* Wv = (const float*)d_in[5];
  const float* bv = (const float*)d_in[6];
  const float* Wp = (const float*)d_in[7];
  const float* bp = (const float*)d_in[8];
  float* out = (float*)d_out;

  char* ws = (char*)d_ws;
  const size_t MB = 1024ull * 1024ull;
  short* Qb  = (short*)(ws + 0);        // [B,H,T,D] bf16 (pre-scaled by log2e/8)
  short* Kb  = (short*)(ws + 8*MB);     // [B,H,T,D] bf16
  short* Vtb = (short*)(ws + 16*MB);    // [B,H,D,T] bf16
  short* AOb = (short*)(ws + 24*MB);    // [B*T, C] bf16 — aliases xb (qkv reads finish first)
  short* xb  = (short*)(ws + 24*MB);    // [M, C] bf16
  short* Wqb = (short*)(ws + 32*MB);
  short* Wkb = (short*)(ws + 34*MB);
  short* Wvb = (short*)(ws + 36*MB);
  short* Wpb = (short*)(ws + 38*MB);
  float* Opart = (float*)(ws + 40*MB);  // 512 x 128x64 f32 partial O (16 MB)
  float* Lpart = (float*)(ws + 56*MB);  // 512 x 128 f32 partial l (256 KB)

  cvt_all<<<8192, 256, 0, stream>>>(x, Wq, Wk, Wv, Wp, xb, Wqb, Wkb, Wvb, Wpb);
  gemm_qkv<<<dim3(8, 32, 3), 256, 0, stream>>>(xb, Wqb, Wkb, Wvb, bq, bk, bv, Qb, Kb, Vtb);
  attn_kernel<<<768, 256, 0, stream>>>(Qb, Kb, Vtb, AOb, Opart, Lpart);
  attn_combine<<<2048, 256, 0, stream>>>(Opart, Lpart, AOb);
  gemm_proj<<<dim3(16, 32), 256, 0, stream>>>(AOb, Wpb, bp, out);
}

// Round 9
// 178.140 us; speedup vs baseline: 1.1353x; 1.0154x over previous
//
#include <hip/hip_runtime.h>
#include <hip/hip_bf16.h>

// B=2, T=2048, C=1024, H=16, D=64, M = B*T = 4096
#define TT 2048
#define MM 4096

typedef __attribute__((ext_vector_type(8))) short bf16x8;
typedef __attribute__((ext_vector_type(4))) float f32x4;

__device__ inline short f2bf(float f){
  union { float f; unsigned u; } x; x.f = f;
  unsigned r = x.u + 0x7FFFu + ((x.u >> 16) & 1u);
  return (short)(r >> 16);
}
__device__ inline int pk2bf(float a, float b){
  __hip_bfloat162 h2 = __float22bfloat162_rn(make_float2(a, b));
  return *(int*)&h2;
}

// async global->LDS, 16B per lane; LDS dest must be wave-uniform base + lane*16
__device__ inline void async16(const void* g, void* l){
  __builtin_amdgcn_global_load_lds((const __attribute__((address_space(1))) void*)g,
                                   (__attribute__((address_space(3))) void*)l, 16, 0, 0);
}

// ---------------- fused fp32 -> bf16 convert (x + 4 weights, one launch) ----------------
__global__ void cvt_all(const float* __restrict__ x,
                        const float* __restrict__ Wq, const float* __restrict__ Wk,
                        const float* __restrict__ Wv, const float* __restrict__ Wp,
                        short* __restrict__ xb, short* __restrict__ Wqb, short* __restrict__ Wkb,
                        short* __restrict__ Wvb, short* __restrict__ Wpb){
  int b = blockIdx.x;
  const float* in; short* out; int base;
  if (b < 4096)      { in = x;  out = xb;  base = b; }
  else if (b < 5120) { in = Wq; out = Wqb; base = b - 4096; }
  else if (b < 6144) { in = Wk; out = Wkb; base = b - 5120; }
  else if (b < 7168) { in = Wv; out = Wvb; base = b - 6144; }
  else               { in = Wp; out = Wpb; base = b - 7168; }
  int i = base * 256 + threadIdx.x;
  float4 v = ((const float4*)in)[i];
  short4 o;
  o.x = f2bf(v.x); o.y = f2bf(v.y); o.z = f2bf(v.z); o.w = f2bf(v.w);
  ((short4*)out)[i] = o;
}

// ---------------- GEMM core: 128x128 tile, BK=32 DOUBLE-BUFFERED single-barrier pipeline ----------------
// R8 post-mortem: R5's dbuf test confounded pipeline with occupancy (64KB LDS -> 2 blocks/CU).
// BK=32 dbuf keeps LDS at 32KB (3 blocks/CU preserved) while adopting the attn kernel's proven
// schedule: barrier -> stage k+1 -> compute k. Each load gets a full compute phase (x12 waves)
// before the barrier that drains it, instead of being drained immediately after issue.
// Barriers: 32 (one per BK-32 step) vs 32 (two per BK-64 step) before -> same count, but no
// zero-distance vmcnt(0) drains. Fragment layout per 32-K panel identical to the old ks-panels.
__device__ inline void gemm_core(const short* __restrict__ A, const short* __restrict__ Wm,
                                 short* As, short* Bs, int m0, int n0,
                                 int tid, int wm, int wn, int quad, int lr,
                                 f32x4 acc[4][4])
{
  const int prow = tid >> 2, pcol = (tid & 3) << 3;
  const short* Ap0 = A  + (size_t)(m0 + prow) * 1024 + pcol;
  const short* Ap1 = Ap0 + 64 * 1024;
  const short* Bp0 = Wm + (size_t)(n0 + prow) * 1024 + pcol;
  const short* Bp1 = Bp0 + 64 * 1024;
  // prologue: K-panel 0 -> buf 0
  async16(Ap0, As + (size_t)tid * 8);
  async16(Ap1, As + (size_t)(tid + 256) * 8);
  async16(Bp0, Bs + (size_t)tid * 8);
  async16(Bp1, Bs + (size_t)(tid + 256) * 8);
  int cur = 0;
  for (int kt = 0; kt < 32; ++kt){
    __syncthreads();                   // buf[cur] staged (issued a full phase ago); prev reads of buf[cur^1] done
    if (kt + 1 < 32){
      const int kk = (kt + 1) * 32;
      short* Ad = As + (cur ^ 1) * 4096;
      short* Bd = Bs + (cur ^ 1) * 4096;
      async16(Ap0 + kk, Ad + (size_t)tid * 8);
      async16(Ap1 + kk, Ad + (size_t)(tid + 256) * 8);
      async16(Bp0 + kk, Bd + (size_t)tid * 8);
      async16(Bp1 + kk, Bd + (size_t)(tid + 256) * 8);
    }
    bf16x8 aF[4], bF[4];
#pragma unroll
    for (int mt = 0; mt < 4; ++mt) aF[mt] = *(const bf16x8*)(As + cur*4096 + (wm*64 + mt*16 + lr)*32 + quad*8);
#pragma unroll
    for (int nt = 0; nt < 4; ++nt) bF[nt] = *(const bf16x8*)(Bs + cur*4096 + (wn*64 + nt*16 + lr)*32 + quad*8);
#pragma unroll
    for (int mt = 0; mt < 4; ++mt)
#pragma unroll
      for (int nt = 0; nt < 4; ++nt)
        acc[mt][nt] = __builtin_amdgcn_mfma_f32_16x16x32_bf16(aF[mt], bF[nt], acc[mt][nt], 0, 0, 0);
    cur ^= 1;
  }
}

// ---------------- QKV projection: Q,K as [B,H,T,D] (Q pre-scaled), V as [B,H,D,T] ----------------
// XCD m-grouped swizzle kept (harmless; unverified benefit). LDS stays 32KB -> 3 blocks/CU.
__launch_bounds__(256, 3)
__global__ void gemm_qkv(const short* __restrict__ A,
                         const short* __restrict__ W0, const short* __restrict__ W1, const short* __restrict__ W2,
                         const float* __restrict__ b0, const float* __restrict__ b1, const float* __restrict__ b2,
                         short* __restrict__ Qo, short* __restrict__ Ko, short* __restrict__ Vt)
{
  __shared__ __align__(16) short smem[16384];
  short* As = smem;                    // 2 bufs x [128 x 32]
  short* Bs = smem + 8192;             // 2 bufs x [128 x 32]
  const int bid = blockIdx.x + (blockIdx.y << 3) + (blockIdx.z << 8);
  const int xcd = bid & 7, slot = bid >> 3;
  const int z   = slot >> 5;                       // 0..2
  const int rem = slot & 31;                       // 4 m-panels x 8 n-panels
  const int m0  = (((xcd << 2) + (rem >> 3))) * 128;
  const int n0  = (rem & 7) * 128;
  const short* Wm   = (z == 0) ? W0 : ((z == 1) ? W1 : W2);
  const float* bias = (z == 0) ? b0 : ((z == 1) ? b1 : b2);
  const int tid = threadIdx.x;
  const int lane = tid & 63, wave = tid >> 6;
  const int wm = wave >> 1, wn = wave & 1;
  const int quad = lane >> 4, lr = lane & 15;

  f32x4 acc[4][4];
#pragma unroll
  for (int i = 0; i < 4; ++i)
#pragma unroll
    for (int j = 0; j < 4; ++j)
#pragma unroll
      for (int r = 0; r < 4; ++r) acc[i][j][r] = 0.f;

  gemm_core(A, Wm, As, Bs, m0, n0, tid, wm, wn, quad, lr, acc);

  const float qscale = 0.125f * 1.4426950408889634f;  // scale/sqrt(D) * log2(e) folded into Q
  const int bB = m0 >> 11, t0 = m0 & 2047;

  if (z == 2){
    // V: transpose in LDS -> coalesced [B,H,D,T] stores
#pragma unroll
    for (int nh = 0; nh < 2; ++nh){
      __syncthreads();
      if (wn == nh){
#pragma unroll
        for (int nt = 0; nt < 4; ++nt){
          int n = n0 + wn*64 + nt*16 + lr;
          float bv = bias[n];
          int n_l = nt*16 + lr;
#pragma unroll
          for (int mt = 0; mt < 4; ++mt)
#pragma unroll
            for (int r = 0; r < 4; ++r){
              int m_l = wm*64 + mt*16 + quad*4 + r;
              smem[n_l*136 + m_l] = f2bf(acc[mt][nt][r] + bv);
            }
        }
      }
      __syncthreads();
#pragma unroll
      for (int i = 0; i < 4; ++i){
        int c = tid + i*256;
        int rowN = c >> 4, ch = c & 15;
        int4 v = *(const int4*)(smem + rowN*136 + ch*8);
        int n = n0 + nh*64 + rowN;
        int hH = n >> 6, d = n & 63;
        *(int4*)(Vt + ((size_t)((bB<<4) + hH)*64 + d)*2048 + t0 + ch*8) = v;
      }
    }
    return;
  }

  // Q/K: stage [m][n] tile half-by-half in LDS (stride 72), then coalesced int4 row stores
  short* dst = (z == 0) ? Qo : Ko;
#pragma unroll
  for (int nh = 0; nh < 2; ++nh){
    __syncthreads();
    if (wn == nh){
#pragma unroll
      for (int nt = 0; nt < 4; ++nt){
        int n_l = nt*16 + lr;
        float bv = bias[n0 + nh*64 + n_l];
#pragma unroll
        for (int mt = 0; mt < 4; ++mt){
#pragma unroll
          for (int r = 0; r < 4; ++r){
            int m_l = wm*64 + mt*16 + quad*4 + r;
            float v = acc[mt][nt][r] + bv;
            if (z == 0) v *= qscale;
            smem[m_l*72 + n_l] = f2bf(v);
          }
        }
      }
    }
    __syncthreads();
    const int hH = (n0 + nh*64) >> 6;
    short* dhead = dst + (size_t)((bB<<4) + hH) * 2048 * 64;
#pragma unroll
    for (int i = 0; i < 4; ++i){
      int c = tid + i*256;
      int rowm = c >> 3, ch = (c & 7) << 3;
      int4 v = *(const int4*)(smem + rowm*72 + ch);
      *(int4*)(dhead + (size_t)(t0 + rowm)*64 + ch) = v;
    }
  }
}

// ---------------- output projection: 128x64 tiles, BK=32 dbuf single-barrier + XCD swizzle ----------------
// Same pipeline conversion; LDS 24KB unchanged. 2 blocks/CU (grid-limited) — intra-block
// overlap is the fix for proj's low block count.
__launch_bounds__(256, 2)
__global__ void gemm_proj(const short* __restrict__ A, const short* __restrict__ Wm,
                          const float* __restrict__ bias, float* __restrict__ out)
{
  __shared__ __align__(16) short As[2*4096];   // 2 bufs x [128 x 32]
  __shared__ __align__(16) short Bs[2*2048];   // 2 bufs x [64 x 32]
  const int bid = blockIdx.x + (blockIdx.y << 4);
  const int xcd = bid & 7, slot = bid >> 3;        // slot in [0,64): 4 m x 16 n
  const int m0  = ((xcd << 2) + (slot >> 4)) * 128;
  const int n0  = (slot & 15) * 64;
  const int tid = threadIdx.x;
  const int lane = tid & 63, wave = tid >> 6;
  const int quad = lane >> 4, lr = lane & 15;

  const int prow = tid >> 2, pcol = (tid & 3) << 3;
  const short* Ap0 = A  + (size_t)(m0 + prow) * 1024 + pcol;
  const short* Ap1 = Ap0 + 64 * 1024;
  const short* Bp0 = Wm + (size_t)(n0 + prow) * 1024 + pcol;

  f32x4 acc[2][4];
#pragma unroll
  for (int i = 0; i < 2; ++i)
#pragma unroll
    for (int j = 0; j < 4; ++j)
#pragma unroll
      for (int r = 0; r < 4; ++r) acc[i][j][r] = 0.f;

  // prologue: K-panel 0 -> buf 0
  async16(Ap0, As + (size_t)tid * 8);
  async16(Ap1, As + (size_t)(tid + 256) * 8);
  if (prow < 64) async16(Bp0, Bs + (size_t)tid * 8);
  int cur = 0;
  for (int kt = 0; kt < 32; ++kt){
    __syncthreads();
    if (kt + 1 < 32){
      const int kk = (kt + 1) * 32;
      short* Ad = As + (cur ^ 1) * 4096;
      short* Bd = Bs + (cur ^ 1) * 2048;
      async16(Ap0 + kk, Ad + (size_t)tid * 8);
      async16(Ap1 + kk, Ad + (size_t)(tid + 256) * 8);
      if (prow < 64) async16(Bp0 + kk, Bd + (size_t)tid * 8);
    }
    bf16x8 aF[2], bF[4];
#pragma unroll
    for (int mt = 0; mt < 2; ++mt) aF[mt] = *(const bf16x8*)(As + cur*4096 + (wave*32 + mt*16 + lr)*32 + quad*8);
#pragma unroll
    for (int nt = 0; nt < 4; ++nt) bF[nt] = *(const bf16x8*)(Bs + cur*2048 + (nt*16 + lr)*32 + quad*8);
#pragma unroll
    for (int mt = 0; mt < 2; ++mt)
#pragma unroll
      for (int nt = 0; nt < 4; ++nt)
        acc[mt][nt] = __builtin_amdgcn_mfma_f32_16x16x32_bf16(aF[mt], bF[nt], acc[mt][nt], 0, 0, 0);
    cur ^= 1;
  }

#pragma unroll
  for (int nt = 0; nt < 4; ++nt){
    int n = n0 + nt*16 + lr;
    float bv = bias[n];
#pragma unroll
    for (int mt = 0; mt < 2; ++mt){
      int mBase = m0 + wave*32 + mt*16 + quad*4;
#pragma unroll
      for (int r = 0; r < 4; ++r){
        int m = mBase + r;
        out[(size_t)m * 1024 + n] = acc[mt][nt][r] + bv;
      }
    }
  }
}

// ---------------- flash attention (causal): 128-row bands, 32 q/wave, 3 blocks/CU ----------------
// Q (pre-scaled by log2e/8), K: [B*H, T, 64] bf16 ; Vt: [B*H, 64, T] bf16 ; AO: [B*T, 1024] bf16
// Verified R4 schedule: 3 co-resident tasks per CU run in PARALLEL; per-CU sum = 34 steps with
// mixed lengths. Bands qb>=8 KV-split into exact-additive halves; combine normalizes t>=1024.
// slice_tbl entry: (qb<<11) | (kv_start<<6) | kv_len ; row a = CU slice, col j = dispatch wave.
__device__ __constant__ int slice_tbl[24] = {
  14352, 30736,     2,   // a=0: U7(16),  Ha15(16), U0(2)
  31760, 26638,  2052,   // a=1: Hb15(16), Ha13(14), U1(4)
  12302, 27534,  4102,   // a=2: U6(14),  Hb13(14), U2(6)
  28687, 20491,  6152,   // a=3: Ha14(15), Ha10(11), U3(8)
  29647, 19082, 16393,   // a=4: Hb14(15), Hb9(10),  Ha8(9)
  24589, 10252, 16969,   // a=5: Ha12(13), U5(12),  Hb8(9)
  25421, 21195,  8202,   // a=6: Hb12(13), Hb10(11), U4(10)
  22540, 23308, 18442    // a=7: Ha11(12), Hb11(12), Ha9(10)
};

__launch_bounds__(256, 3)
__global__ void attn_kernel(const short* __restrict__ Q, const short* __restrict__ K,
                            const short* __restrict__ Vt, short* __restrict__ AO,
                            float* __restrict__ Opart, float* __restrict__ Lpart)
{
  __shared__ __align__(16) short Ks[2][4096];   // [buf][64 rows x 64 shorts], swizzled
  __shared__ __align__(16) short Vs[2][4096];
  __shared__ __align__(16) short Ps[8192];      // per-wave 2x(16x64) P^T/O^T scratch, swizzled
  const int tid = threadIdx.x, lane = tid & 63, wave = tid >> 6;
  const int quad = lane >> 4, lr = lane & 15;
  const int bid = blockIdx.x;
  const int a = (bid >> 5) & 7;                // CU slice
  const int hb = bid & 31;
  const int j = bid >> 8;                      // dispatch wave 0..2 (j*256 apart -> same CU)
  const int e = slice_tbl[a*3 + j];
  const int qb = e >> 11, kv_s = (e >> 6) & 31, kvn = e & 63;
  const bool split = (kvn != 2*qb + 2);
  const int half = (kv_s != 0) ? 1 : 0;
  const int bidx = hb >> 4, h = hb & 15;
  const int wq0 = qb * 128 + wave * 32;        // this wave's 32 q-rows (two 16-row groups)
  const short* Qh = Q  + (size_t)hb * TT * 64;
  const short* Kh = K  + (size_t)hb * TT * 64;
  const short* Vh = Vt + (size_t)hb * 64 * TT;
  short* Pw = Ps + wave * 2048;                // two 1024-short regions (one per q-group)

  // staging: chunk c = tid covers (row = c>>3, swizzled col-chunk); c+256 = row+32, same swizzle
  const int srow = tid >> 3;
  const int ssw  = (tid & 7) ^ (srow & 7);
  const short* Kp0 = Kh + (size_t)srow * 64 + ssw * 8;
  const short* Vp0 = Vh + (size_t)srow * TT + ssw * 8;

  // loop-invariant Q fragments (B-operand: n = lr = q), one pair per q-group
  bf16x8 qf[2][2];
#pragma unroll
  for (int g = 0; g < 2; ++g)
#pragma unroll
    for (int ks = 0; ks < 2; ++ks)
      qf[g][ks] = *(const bf16x8*)(Qh + (size_t)(wq0 + g*16 + lr) * 64 + ks*32 + quad*8);

  // swizzled frag-read chunk offsets (loop-invariant): chunk ks*4+quad, row-phase lr&7
  const int lsw0 = (((0*4 + quad) ^ (lr & 7)) << 3);
  const int lsw1 = (((1*4 + quad) ^ (lr & 7)) << 3);
  const int qh2 = quad >> 1, qlo = (quad & 1) << 2;

  f32x4 acc_o[2][4], l_acc[2];
#pragma unroll
  for (int g = 0; g < 2; ++g){
#pragma unroll
    for (int r = 0; r < 4; ++r) l_acc[g][r] = 0.f;
#pragma unroll
    for (int dt = 0; dt < 4; ++dt)
#pragma unroll
      for (int r = 0; r < 4; ++r) acc_o[g][dt][r] = 0.f;
  }

  const short one_bf = (short)0x3F80;
  const bf16x8 onesf = { one_bf, one_bf, one_bf, one_bf, one_bf, one_bf, one_bf, one_bf };

  const int kv_e = kv_s + kvn;
  const int qtw = wq0 >> 6;                    // wave's diagonal KV-tile (both q-groups share it)
  // prologue: stage tile kv_s into buffer 0 (async)
  {
    const short* kp = Kp0 + (size_t)kv_s * 4096;
    const short* vp = Vp0 + kv_s * 64;
    async16(kp,          &Ks[0][(size_t)tid * 8]);
    async16(kp + 32*64,  &Ks[0][(size_t)(tid + 256) * 8]);
    async16(vp,          &Vs[0][(size_t)tid * 8]);
    async16(vp + 32*TT,  &Vs[0][(size_t)(tid + 256) * 8]);
  }

  // strength-reduced next-tile staging pointers
  const short* kp_n = Kp0 + (size_t)(kv_s + 1) * 4096;
  const short* vp_n = Vp0 + (kv_s + 1) * 64;

  int cur = 0;
  for (int kv = kv_s; kv < kv_e; ++kv){
    const int kv0 = kv * 64;
    __syncthreads();                     // drains vmcnt: buf[cur] ready; prior reads of buf[cur^1] done
    if (kv + 1 < kv_e){                  // async stage tile kv+1 into the other buffer
      const int nb = cur ^ 1;
      async16(kp_n,          &Ks[nb][(size_t)tid * 8]);
      async16(kp_n + 32*64,  &Ks[nb][(size_t)(tid + 256) * 8]);
      async16(vp_n,          &Vs[nb][(size_t)tid * 8]);
      async16(vp_n + 32*TT,  &Vs[nb][(size_t)(tid + 256) * 8]);
      kp_n += 4096; vp_n += 64;
    }
    if (kv0 <= wq0 + 31){
      __builtin_amdgcn_s_setprio(1);     // favor compute waves over co-resident stagers (m191)
      // S^T = K Q^T for both q-groups; each kf fragment read once, used twice
      f32x4 s4[2][4];
#pragma unroll
      for (int g = 0; g < 2; ++g)
#pragma unroll
        for (int nt = 0; nt < 4; ++nt)
#pragma unroll
          for (int r = 0; r < 4; ++r) s4[g][nt][r] = 0.f;
#pragma unroll
      for (int nt = 0; nt < 4; ++nt){
        bf16x8 kf0 = *(const bf16x8*)(&Ks[cur][(nt*16 + lr)*64 + lsw0]);
        bf16x8 kf1 = *(const bf16x8*)(&Ks[cur][(nt*16 + lr)*64 + lsw1]);
#pragma unroll
        for (int g = 0; g < 2; ++g){
          s4[g][nt] = __builtin_amdgcn_mfma_f32_16x16x32_bf16(kf0, qf[g][0], s4[g][nt], 0, 0, 0);
          s4[g][nt] = __builtin_amdgcn_mfma_f32_16x16x32_bf16(kf1, qf[g][1], s4[g][nt], 0, 0, 0);
        }
      }

      // P^T = exp2(S^T); diagonal-tile masking hoisted into a wave-uniform branch
      if (kv == qtw){
#pragma unroll
        for (int g = 0; g < 2; ++g){
          const int qglob = wq0 + g*16 + lr;
          short* Pg = Pw + g*1024;
#pragma unroll
          for (int nt = 0; nt < 4; ++nt){
            const int keyb = kv0 + nt*16 + quad*4;
            float pv[4];
#pragma unroll
            for (int r = 0; r < 4; ++r){
              float v = exp2f(s4[g][nt][r]);
              if (keyb + r > qglob) v = 0.f;
              pv[r] = v;
            }
            int2 w;
            w.x = pk2bf(pv[0], pv[1]);
            w.y = pk2bf(pv[2], pv[3]);
            const int gg = nt*2 + qh2;
            *(int2*)(Pg + lr*64 + ((gg ^ (lr & 7)) << 3) + qlo) = w;
          }
        }
      } else {
#pragma unroll
        for (int g = 0; g < 2; ++g){
          short* Pg = Pw + g*1024;
#pragma unroll
          for (int nt = 0; nt < 4; ++nt){
            int2 w;
            w.x = pk2bf(exp2f(s4[g][nt][0]), exp2f(s4[g][nt][1]));
            w.y = pk2bf(exp2f(s4[g][nt][2]), exp2f(s4[g][nt][3]));
            const int gg = nt*2 + qh2;
            *(int2*)(Pg + lr*64 + ((gg ^ (lr & 7)) << 3) + qlo) = w;
          }
        }
      }
      // wave-private Pw: lgkmcnt ordering only, no barrier

      // l += 1^T P^T ; O^T += V^T P^T ; each vf fragment read once, used twice
#pragma unroll
      for (int ks = 0; ks < 2; ++ks){
        const int lsw = ks ? lsw1 : lsw0;
        bf16x8 ptf0 = *(const bf16x8*)(Pw + lr*64 + lsw);
        bf16x8 ptf1 = *(const bf16x8*)(Pw + 1024 + lr*64 + lsw);
        l_acc[0] = __builtin_amdgcn_mfma_f32_16x16x32_bf16(onesf, ptf0, l_acc[0], 0, 0, 0);
        l_acc[1] = __builtin_amdgcn_mfma_f32_16x16x32_bf16(onesf, ptf1, l_acc[1], 0, 0, 0);
#pragma unroll
        for (int dt = 0; dt < 4; ++dt){
          bf16x8 vf = *(const bf16x8*)(&Vs[cur][(dt*16 + lr)*64 + lsw]);
          acc_o[0][dt] = __builtin_amdgcn_mfma_f32_16x16x32_bf16(vf, ptf0, acc_o[0][dt], 0, 0, 0);
          acc_o[1][dt] = __builtin_amdgcn_mfma_f32_16x16x32_bf16(vf, ptf1, acc_o[1][dt], 0, 0, 0);
        }
      }
      __builtin_amdgcn_s_setprio(0);
    }
    cur ^= 1;
  }

  if (split){
    // partial epilogue: raw fp32 O + l to workspace; exact additive combine later (no max-rescale)
    const int p = (((hb << 3) | (qb - 8)) << 1) + half;
    float* Op = Opart + (size_t)p * 8192;     // [128 q][64 d] f32
#pragma unroll
    for (int g = 0; g < 2; ++g){
      const int q_l = wave*32 + g*16 + lr;
#pragma unroll
      for (int dt = 0; dt < 4; ++dt)
        *(f32x4*)(Op + q_l*64 + dt*16 + quad*4) = acc_o[g][dt];
      if (lane < 16) Lpart[p*128 + wave*32 + g*16 + lane] = l_acc[g][0];
    }
    return;
  }

  // epilogue (unsplit): O = O^T / l per q-group; transpose via swizzled wave-private LDS -> int4 stores
#pragma unroll
  for (int g = 0; g < 2; ++g){
    short* Pg = Pw + g*1024;
    const float inv = __builtin_amdgcn_rcpf(l_acc[g][0]);   // all regs equal l[q=lr]
#pragma unroll
    for (int dt = 0; dt < 4; ++dt){
      int2 w;
      w.x = pk2bf(acc_o[g][dt][0] * inv, acc_o[g][dt][1] * inv);
      w.y = pk2bf(acc_o[g][dt][2] * inv, acc_o[g][dt][3] * inv);
      const int gg = dt*2 + qh2;
      *(int2*)(Pg + lr*64 + ((gg ^ (lr & 7)) << 3) + qlo) = w;
    }
    // wave-private: compiler inserts lgkmcnt wait before the reads below
#pragma unroll
    for (int i = 0; i < 2; ++i){
      int c = lane + i*64;               // 128 chunks: 16 q-rows x 8 chunks of 8 shorts
      int row = c >> 3, ch = c & 7;
      int4 v = *(const int4*)(Pg + row*64 + ((ch ^ (row & 7)) << 3));
      *(int4*)(AO + (size_t)(bidx*2048 + wq0 + g*16 + row)*1024 + h*64 + ch*8) = v;
    }
  }
}

// ---------------- combine: O = (O0+O1)/(l0+l1) for split bands (t >= 1024 per batch) ----------------
__global__ void attn_combine(const float* __restrict__ Opart, const float* __restrict__ Lpart,
                             short* __restrict__ AO)
{
  const int gid = blockIdx.x * 256 + threadIdx.x;  // 524288 = 32768 rows x 16 d-quads
  const int row = gid >> 4, dq = (gid & 15) << 2;
  const int hb = row >> 10, band = (row >> 7) & 7, r = row & 127;
  const int p = ((hb << 3) | band) << 1;
  const f32x4 a = *(const f32x4*)(Opart + (size_t)p*8192 + r*64 + dq);
  const f32x4 b = *(const f32x4*)(Opart + (size_t)(p+1)*8192 + r*64 + dq);
  const float l = Lpart[p*128 + r] + Lpart[(p+1)*128 + r];
  const float inv = __builtin_amdgcn_rcpf(l);
  int2 w;
  w.x = pk2bf((a[0]+b[0])*inv, (a[1]+b[1])*inv);
  w.y = pk2bf((a[2]+b[2])*inv, (a[3]+b[3])*inv);
  const int t = (8 + band)*128 + r;
  const int bidx = hb >> 4, h = hb & 15;
  *(int2*)(AO + (size_t)(bidx*2048 + t)*1024 + h*64 + dq) = w;
}

extern "C" void kernel_launch(void* const* d_in, const int* in_sizes, int n_in,
                              void* d_out, int out_size, void* d_ws, size_t ws_size,
                              hipStream_t stream)
{
  const float* x  = (const float*)d_in[0];
  const float* Wq = (const float*)d_in[1];
  const float* bq = (const float*)d_in[2];
  const float* Wk = (const float*)d_in[3];
  const float* bk = (const float*)d_in[4];
  const float* Wv = (const float*)d_in[5];
  const float* bv = (const float*)d_in[6];
  const float* Wp = (const float*)d_in[7];
  const float* bp = (const float*)d_in[8];
  float* out = (float*)d_out;

  char* ws = (char*)d_ws;
  const size_t MB = 1024ull * 1024ull;
  short* Qb  = (short*)(ws + 0);        // [B,H,T,D] bf16 (pre-scaled by log2e/8)
  short* Kb  = (short*)(ws + 8*MB);     // [B,H,T,D] bf16
  short* Vtb = (short*)(ws + 16*MB);    // [B,H,D,T] bf16
  short* AOb = (short*)(ws + 24*MB);    // [B*T, C] bf16 — aliases xb (qkv reads finish first)
  short* xb  = (short*)(ws + 24*MB);    // [M, C] bf16
  short* Wqb = (short*)(ws + 32*MB);
  short* Wkb = (short*)(ws + 34*MB);
  short* Wvb = (short*)(ws + 36*MB);
  short* Wpb = (short*)(ws + 38*MB);
  float* Opart = (float*)(ws + 40*MB);  // 512 x 128x64 f32 partial O (16 MB)
  float* Lpart = (float*)(ws + 56*MB);  // 512 x 128 f32 partial l (256 KB)

  cvt_all<<<8192, 256, 0, stream>>>(x, Wq, Wk, Wv, Wp, xb, Wqb, Wkb, Wvb, Wpb);
  gemm_qkv<<<dim3(8, 32, 3), 256, 0, stream>>>(xb, Wqb, Wkb, Wvb, bq, bk, bv, Qb, Kb, Vtb);
  attn_kernel<<<768, 256, 0, stream>>>(Qb, Kb, Vtb, AOb, Opart, Lpart);
  attn_combine<<<2048, 256, 0, stream>>>(Opart, Lpart, AOb);
  gemm_proj<<<dim3(16, 32), 256, 0, stream>>>(AOb, Wpb, bp, out);
}